// Round 3
// baseline (1363.721 us; speedup 1.0000x reference)
//
#include <hip/hip_runtime.h>
#include <cstdint>
#include <cstddef>

// ---------------------------------------------------------------------------
// GateLoop block, round 8: phase-structured GEMM (T3+T4+T5).
//   mgemm rewritten: 128x256 tile, BK=32, 8 waves (2Mx4N, 64x64/wave),
//   3 LDS buffers (72 KiB -> 2 blocks/CU), prefetch distance 2 K-tiles,
//   counted s_waitcnt vmcnt(3) (never 0 in main loop), raw s_barrier
//   (NOT __syncthreads -- that emits vmcnt(0) and kills the pipeline),
//   s_setprio(1) around the 16-MFMA cluster. Loop unrolled x3 for static
//   buffer indices (runtime-indexed arrays -> scratch, rule #20).
//   Correctness: wait-then-barrier = each wave drains its OWN tile-(t+1)
//   loads (vmcnt(3) leaves only the 3 newest = tile t+2) before the
//   rendezvous; after the barrier all waves' stores have landed.
//   Staging + fragment chunk-XOR swizzle byte-identical to r7 (proven 0
//   bank conflicts).
//   Carried: XCD-chunked swizzle, fast gelu/sigmoid, consolidated
//   projections, vectorized pointwise kernels.
//
// Pipeline:
//   0. x -> fp16; weights -> transposed fp16 [N,K] (qkvg stacked)
//   1. mgemm x@[Wq|Wk|Wv|Wg] -> P[M,4096]; x@Wa -> ab (d_out)
//   2. a_transform in place (fp16, d_out)
//   3. chunked scan (3 passes, fp32 state); k*v inline;
//      pass3 writes y in-place over P's q columns
//   4. gn_gate + silu(g) (vectorized, in place on y cols of P)
//   5. mgemm y@Wo -> yo (d_out); ln1 -> x1 (xb slot)
//   6. mgemm x1@W1(+b1,fast gelu) -> h1 (overlays P); h1@W2(+b2) -> h2 (d_out)
//   7. ln2(x1 + h2) -> out (in place over h2)
//
// ws layout (MiB): 0 W1T(8) | 8 W2T(8) | 16 PWT(8) | 24 WoT(2) | 26 WaT(4) |
//   30 chunk(4) | 34 carry(2) | 36 stats | 37 xb(32) | 69 P(128) | 197 end.
// Aliases: ab & yo & h2 -> d_out; y over P q-cols; h1 -> P; x1 -> xb.
// ---------------------------------------------------------------------------

#define EPSN 1e-6f

typedef _Float16 f16;
typedef _Float16 f16x8 __attribute__((ext_vector_type(8)));
typedef _Float16 f16x4 __attribute__((ext_vector_type(4)));
typedef float    f32x4 __attribute__((ext_vector_type(4)));

static constexpr int    Bb     = 4;
static constexpr int    Ss     = 4096;
static constexpr int    Dd     = 1024;
static constexpr int    Ff     = 4096;
static constexpr int    Mrows  = Bb * Ss;                  // 16384
static constexpr size_t MD     = (size_t)Mrows * Dd;       // 16777216
static constexpr int    CHUNKS = 64;
static constexpr int    CLEN   = Ss / CHUNKS;              // 64
static constexpr int    BD     = Bb * Dd;                  // 4096
static constexpr int    CBD    = CHUNKS * BD;              // 262144
static constexpr size_t MiB    = 1024 * 1024;
static constexpr int    PLD    = 4096;                     // P row stride

__device__ __forceinline__ float fast_sigmoid(float x) {
    float e = __builtin_amdgcn_exp2f(-1.4426950408889634f * x);
    return __builtin_amdgcn_rcpf(1.0f + e);
}
__device__ __forceinline__ float gelu_tanh(float x) {
    float z = 0.7978845608028654f * (x + 0.044715f * x * x * x);
    z = fminf(fmaxf(z, -10.0f), 10.0f);          // tanh(+-10)=+-1 to fp32
    float e = __builtin_amdgcn_exp2f(2.885390081777927f * z);   // e^{2z}
    float t = (e - 1.0f) * __builtin_amdgcn_rcpf(e + 1.0f);
    return 0.5f * x * (1.0f + t);
}

// async global->LDS, 16 B per lane; lds dest = base + lane*16 (wave-uniform base)
__device__ __forceinline__ void async16(const void* g, void* l) {
    __builtin_amdgcn_global_load_lds(
        (const __attribute__((address_space(1))) unsigned int*)(uintptr_t)g,
        (__attribute__((address_space(3))) unsigned int*)(uintptr_t)l,
        16, 0, 0);
}

// ------- MFMA GEMM: C[M,N](ldc) = A[M,K](lda,f16) @ Bt[N,K](f16)^T ----------
// Tile 128x256, BK=32, 8 waves of 64x64, 3-buffer pipelined staging.
// EPI: 0 none | 1 bias+gelu | 2 bias
template <int EPI, typename TC>
__global__ __launch_bounds__(512, 4) void mgemm_k(const f16* __restrict__ A, int lda,
                                                  const f16* __restrict__ Bt,
                                                  TC* __restrict__ C, int ldc,
                                                  int M, int N, int K,
                                                  const float* __restrict__ bias) {
    __shared__ f16 sA[3][128 * 32];   // 8 KiB / buffer
    __shared__ f16 sB[3][256 * 32];   // 16 KiB / buffer
    const int tid  = threadIdx.x;
    const int wave = tid >> 6;        // 0..7
    const int lane = tid & 63;

    // XCD-chunked bijective swizzle (all grids have nwg % 8 == 0)
    const int gx  = gridDim.x;
    const int nwg = gx * gridDim.y;
    int bid = blockIdx.y * gx + blockIdx.x;
    bid = (bid & 7) * (nwg >> 3) + (bid >> 3);
    const int bm = (bid / gx) * 128;
    const int bn = (bid % gx) * 256;

    const int rw = (wave >> 2) * 64;  // wave row offset in tile (0,64)
    const int cw = (wave & 3) * 64;   // wave col offset in tile (0..192)

    // staging swizzle (r7-proven): lane l owns LDS (row16=l>>2, chunk=l&3);
    // fetches global chunk (l&3)^((l>>3)&3)
    const int swzc = (((lane & 3) ^ (lane >> 3)) & 3) * 8;
    // wave w stages: A rows [w*16,w*16+16) | B rows [w*16,..) | B rows [128+w*16,..)
    const f16* gS0 = A  + (size_t)(bm + wave * 16 + (lane >> 2)) * lda + swzc;
    const f16* gS1 = Bt + (size_t)(bn + wave * 16 + (lane >> 2)) * K   + swzc;
    const f16* gS2 = Bt + (size_t)(bn + 128 + wave * 16 + (lane >> 2)) * K + swzc;

    f32x4 acc[4][4] = {};

    // fragment read swizzle (r7-proven)
    const int fr  = lane & 15;
    const int fco = (((lane >> 4) ^ (lane >> 1)) & 3) * 8;

    const int NT = K >> 5;            // K-tiles of 32 (K in {1024,4096})

    // prologue: stage tiles 0 and 1; drain tile 0 (leave tile 1's 3 loads)
    async16(gS0,      &sA[0][wave * 512]);
    async16(gS1,      &sB[0][wave * 512]);
    async16(gS2,      &sB[0][(8 + wave) * 512]);
    async16(gS0 + 32, &sA[1][wave * 512]);
    async16(gS1 + 32, &sB[1][wave * 512]);
    async16(gS2 + 32, &sB[1][(8 + wave) * 512]);
    asm volatile("s_waitcnt vmcnt(3)" ::: "memory");
    __builtin_amdgcn_s_barrier();

#define MG_PHASE(T, BR, BS)                                                    \
    {                                                                          \
        const int t_ = (T);                                                    \
        f16x8 af[4], bfr[4];                                                   \
        _Pragma("unroll") for (int i = 0; i < 4; ++i)                          \
            af[i] = *(const f16x8*)&sA[BR][(rw + i * 16 + fr) * 32 + fco];     \
        _Pragma("unroll") for (int j = 0; j < 4; ++j)                          \
            bfr[j] = *(const f16x8*)&sB[BR][(cw + j * 16 + fr) * 32 + fco];    \
        if (t_ + 2 < NT) {                                                     \
            const int kk = (t_ + 2) * 32;                                      \
            async16(gS0 + kk, &sA[BS][wave * 512]);                            \
            async16(gS1 + kk, &sB[BS][wave * 512]);                            \
            async16(gS2 + kk, &sB[BS][(8 + wave) * 512]);                      \
            asm volatile("s_waitcnt vmcnt(3)" ::: "memory");                   \
        } else {                                                               \
            asm volatile("s_waitcnt vmcnt(0)" ::: "memory");                   \
        }                                                                      \
        __builtin_amdgcn_s_barrier();                                          \
        __builtin_amdgcn_s_setprio(1);                                         \
        _Pragma("unroll") for (int i = 0; i < 4; ++i)                          \
            _Pragma("unroll") for (int j = 0; j < 4; ++j)                      \
                acc[i][j] = __builtin_amdgcn_mfma_f32_16x16x32_f16(            \
                    af[i], bfr[j], acc[i][j], 0, 0, 0);                        \
        __builtin_amdgcn_s_setprio(0);                                         \
        __builtin_amdgcn_s_barrier();                                          \
    }

    int t = 0;
    for (; t + 3 <= NT; t += 3) {
        MG_PHASE(t,     0, 2)
        MG_PHASE(t + 1, 1, 0)
        MG_PHASE(t + 2, 2, 1)
    }
    if (t     < NT) MG_PHASE(t,     0, 2)   // t % 3 == 0 at loop exit
    if (t + 1 < NT) MG_PHASE(t + 1, 1, 0)
#undef MG_PHASE

    // epilogue: C row = (lane>>4)*4 + reg, col = lane&15  (dtype-independent)
    const int er = (lane >> 4) * 4;
    const int ec = lane & 15;
#pragma unroll
    for (int i = 0; i < 4; ++i) {
#pragma unroll
        for (int j = 0; j < 4; ++j) {
            const int col = bn + cw + j * 16 + ec;
#pragma unroll
            for (int r = 0; r < 4; ++r) {
                const size_t row = (size_t)(bm + rw + i * 16 + er + r);
                float o = acc[i][j][r];
                if (EPI == 1 || EPI == 2) o += bias[col];
                if (EPI == 1) o = gelu_tanh(o);
                if (sizeof(TC) == 4) ((float*)C)[row * ldc + col] = o;
                else                 ((f16*)C)[row * ldc + col] = (f16)o;
            }
        }
    }
}

// ---------------- weight transpose+convert: Wt[n][k] = f16(W[k][n]) ---------
__global__ __launch_bounds__(256) void wtrans_k(const float* __restrict__ W,
                                                f16* __restrict__ Wt,
                                                int K, int N) {
    __shared__ float t[32][33];
    const int n0 = blockIdx.x * 32, k0 = blockIdx.y * 32;
    const int tx = threadIdx.x & 31, ty = threadIdx.x >> 5;   // 8 rows
#pragma unroll
    for (int i = 0; i < 32; i += 8)
        t[ty + i][tx] = W[(size_t)(k0 + ty + i) * N + n0 + tx];
    __syncthreads();
#pragma unroll
    for (int i = 0; i < 32; i += 8)
        Wt[(size_t)(n0 + ty + i) * K + k0 + tx] = (f16)t[tx][ty + i];
}

// ---------------- x fp32 -> fp16 --------------------------------------------
__global__ __launch_bounds__(256) void f2h_k(const float* __restrict__ x,
                                             f16* __restrict__ xh) {
    size_t i = ((size_t)blockIdx.x * 256 + threadIdx.x) * 4;
    float4 v = *(const float4*)&x[i];
    f16x4 s;
    s.x = (f16)v.x; s.y = (f16)v.y; s.z = (f16)v.z; s.w = (f16)v.w;
    *(f16x4*)&xh[i] = s;
}

// ------- a transform: a_c = sigmoid(|a|)*a/|a| (fp16 in place, x8) ----------
__global__ __launch_bounds__(256) void a_transform_k(f16* __restrict__ a2d) {
    size_t gid = (size_t)blockIdx.x * 256 + threadIdx.x;   // < M*D/8
    int    j8  = (int)(gid & 127) * 8;
    size_t row = gid >> 7;
    f16x8 vr = *(f16x8*)&a2d[row * 2048 + j8];
    f16x8 vi = *(f16x8*)&a2d[row * 2048 + 1024 + j8];
#pragma unroll
    for (int i = 0; i < 8; ++i) {
        float ar = (float)vr[i], ai = (float)vi[i];
        float mag = sqrtf(ar * ar + ai * ai);
        float sg  = fast_sigmoid(mag);
        float re, im;
        if (mag > 1e-30f) { float s = sg * __builtin_amdgcn_rcpf(mag); re = ar * s; im = ai * s; }
        else              { re = sg; im = 0.0f; }
        vr[i] = (f16)re; vi[i] = (f16)im;
    }
    *(f16x8*)&a2d[row * 2048 + j8]        = vr;
    *(f16x8*)&a2d[row * 2048 + 1024 + j8] = vi;
}

// ---------------- chunked complex scan (fp32 state) -------------------------
// P columns: q 0..1023 | k 1024..2047 | v 2048..3071 | g 3072..4095
__global__ __launch_bounds__(256) void scan_pass1_k(const f16* __restrict__ a2d,
                                                    const f16* __restrict__ P,
                                                    float4* __restrict__ chunk) {
    int tid = blockIdx.x * 256 + threadIdx.x;    // < CBD
    int d   = tid & 1023;
    int t1  = tid >> 10;
    int b   = t1 & 3;
    int c   = t1 >> 2;
    int t0  = c * CLEN;
    int rbase = b * Ss;
    float Are = 1.0f, Aim = 0.0f, Hre = 0.0f, Him = 0.0f;
    for (int t = t0; t < t0 + CLEN; ++t) {
        int r = rbase + t;
        float are = (float)a2d[(size_t)r * 2048 + d];
        float aim = (float)a2d[(size_t)r * 2048 + 1024 + d];
        float kvv = (float)P[(size_t)r * PLD + 1024 + d]
                  * (float)P[(size_t)r * PLD + 2048 + d];
        float hre = are * Hre - aim * Him + kvv;
        float him = are * Him + aim * Hre;
        Hre = hre; Him = him;
        float pre = are * Are - aim * Aim;
        float pim = are * Aim + aim * Are;
        Are = pre; Aim = pim;
    }
    chunk[tid] = make_float4(Are, Aim, Hre, Him);
}

__global__ __launch_bounds__(256) void scan_pass2_k(const float4* __restrict__ chunk,
                                                    float2* __restrict__ carry,
                                                    float* __restrict__ stats) {
    int tid = blockIdx.x * blockDim.x + threadIdx.x;  // < B*D = 4096
    if (tid < 512) stats[tid] = 0.0f;                 // ws is poisoned: zero gn stats
    float hre = 0.0f, him = 0.0f;
    for (int c = 0; c < CHUNKS; ++c) {
        int task = c * BD + tid;
        float4 ch = chunk[task];
        carry[task] = make_float2(hre, him);
        float nre = ch.x * hre - ch.y * him + ch.z;
        float nim = ch.x * him + ch.y * hre + ch.w;
        hre = nre; him = nim;
    }
}

// pass3: y written in place over P's q columns (per-elem read-then-write)
__global__ __launch_bounds__(256) void scan_pass3_k(const f16* __restrict__ a2d,
                                                    f16* __restrict__ P,
                                                    const float2* __restrict__ carry,
                                                    float* __restrict__ stats) {
    int tid = blockIdx.x * 256 + threadIdx.x;    // < CBD
    int d   = tid & 1023;
    int t1  = tid >> 10;
    int b   = t1 & 3;
    int c   = t1 >> 2;
    int t0  = c * CLEN;
    int rbase = b * Ss;
    float2 cr = carry[tid];
    float hre = cr.x, him = cr.y;
    float sre = 0.0f, sim = 0.0f, s2 = 0.0f;
    for (int t = t0; t < t0 + CLEN; ++t) {
        int r = rbase + t;
        float are = (float)a2d[(size_t)r * 2048 + d];
        float aim = (float)a2d[(size_t)r * 2048 + 1024 + d];
        float kvv = (float)P[(size_t)r * PLD + 1024 + d]
                  * (float)P[(size_t)r * PLD + 2048 + d];
        float nre = are * hre - aim * him + kvv;
        float nim = are * him + aim * hre;
        hre = nre; him = nim;
        float qv  = (float)P[(size_t)r * PLD + d];
        float yr_ = qv * hre;
        float yi_ = qv * him;
        P[(size_t)r * PLD + d] = (f16)yr_;       // overwrite q with y (safe)
        sre += yr_; sim += yi_; s2 += yr_ * yr_ + yi_ * yi_;
    }
#pragma unroll
    for (int off = 16; off > 0; off >>= 1) {
        sre += __shfl_down(sre, off, 32);
        sim += __shfl_down(sim, off, 32);
        s2  += __shfl_down(s2,  off, 32);
    }
    if ((threadIdx.x & 31) == 0) {
        int idx = (b * 32 + (d >> 5)) * 4;
        atomicAdd(&stats[idx + 0], sre);
        atomicAdd(&stats[idx + 1], sim);
        atomicAdd(&stats[idx + 2], s2);
    }
}

// ------- groupnorm (real) + silu(g)-gate, f16x8, in place on y cols ---------
__global__ __launch_bounds__(256) void gn_gate_k(f16* __restrict__ P,
                                                 const float* __restrict__ stats,
                                                 const float* __restrict__ gn_scale,
                                                 const float* __restrict__ gn_bias) {
    size_t gid = (size_t)blockIdx.x * 256 + threadIdx.x;  // < M*D/8
    int d8  = (int)(gid & 127) * 8;
    int row = (int)(gid >> 7);
    int b   = row >> 12;
    int grp = d8 >> 5;
    const float* st = &stats[(b * 32 + grp) * 4];
    const float invN = 1.0f / 131072.0f;       // S * (D/G)
    float mre = st[0] * invN;
    float mim = st[1] * invN;
    float var = st[2] * invN - mre * mre - mim * mim;
    float rstd = rsqrtf(var + EPSN);
    f16x8 yv = *(f16x8*)&P[(size_t)row * PLD + d8];
    f16x8 gv = *(const f16x8*)&P[(size_t)row * PLD + 3072 + d8];
#pragma unroll
    for (int i = 0; i < 8; ++i) {
        float re = ((float)yv[i] - mre) * rstd * gn_scale[d8 + i] + gn_bias[d8 + i];
        float gx = (float)gv[i];
        yv[i] = (f16)(re * gx * fast_sigmoid(gx));
    }
    *(f16x8*)&P[(size_t)row * PLD + d8] = yv;
}

// ---------------- layernorm over D=1024: out = LN(a + b) --------------------
__device__ __forceinline__ float ldf(const float* p, size_t i) { return p[i]; }
__device__ __forceinline__ float ldf(const f16* p, size_t i)   { return (float)p[i]; }
__device__ __forceinline__ void  stf(float* p, size_t i, float v) { p[i] = v; }
__device__ __forceinline__ void  stf(f16* p, size_t i, float v)   { p[i] = (f16)v; }

__device__ __forceinline__ float block_reduce_sum(float v, float* s4, int tid) {
#pragma unroll
    for (int off = 32; off > 0; off >>= 1) v += __shfl_down(v, off, 64);
    __syncthreads();
    if ((tid & 63) == 0) s4[tid >> 6] = v;
    __syncthreads();
    return s4[0] + s4[1] + s4[2] + s4[3];
}

template <typename TA, typename TB, typename TO>
__global__ __launch_bounds__(256) void ln_k(const TA* __restrict__ a,
                                            const TB* __restrict__ b,
                                            const float* __restrict__ scale,
                                            const float* __restrict__ bias,
                                            TO* __restrict__ out) {
    __shared__ float s4[4];
    int row = blockIdx.x;
    size_t base = (size_t)row * 1024;
    int tid = threadIdx.x;
    float v[4];
    float s = 0.0f;
#pragma unroll
    for (int i = 0; i < 4; ++i) {
        int d = tid + i * 256;
        v[i] = ldf(a, base + d) + ldf(b, base + d);
        s += v[i];
    }
    float mu = block_reduce_sum(s, s4, tid) * (1.0f / 1024.0f);
    float s2 = 0.0f;
#pragma unroll
    for (int i = 0; i < 4; ++i) {
        float dv = v[i] - mu;
        s2 += dv * dv;
    }
    float var = block_reduce_sum(s2, s4, tid) * (1.0f / 1024.0f);
    float rstd = rsqrtf(var + EPSN);
#pragma unroll
    for (int i = 0; i < 4; ++i) {
        int d = tid + i * 256;
        stf(out, base + d, (v[i] - mu) * rstd * scale[d] + bias[d]);
    }
}

// ---------------------------------------------------------------------------
extern "C" void kernel_launch(void* const* d_in, const int* in_sizes, int n_in,
                              void* d_out, int out_size, void* d_ws, size_t ws_size,
                              hipStream_t stream) {
    const float* x        = (const float*)d_in[0];
    const float* Wq       = (const float*)d_in[1];
    const float* Wk       = (const float*)d_in[2];
    const float* Wv       = (const float*)d_in[3];
    const float* Wa       = (const float*)d_in[4];
    const float* Wg       = (const float*)d_in[5];
    const float* Wo       = (const float*)d_in[6];
    const float* gn_scale = (const float*)d_in[7];
    const float* gn_bias  = (const float*)d_in[8];
    const float* ln1_s    = (const float*)d_in[9];
    const float* ln1_b    = (const float*)d_in[10];
    const float* W1       = (const float*)d_in[11];
    const float* b1       = (const float*)d_in[12];
    const float* W2       = (const float*)d_in[13];
    const float* b2       = (const float*)d_in[14];
    const float* ln2_s    = (const float*)d_in[15];
    const float* ln2_b    = (const float*)d_in[16];
    float* out = (float*)d_out;

    char* base = (char*)d_ws;
    f16* W1T = (f16*)(base + 0 * MiB);    // [4096, 1024]
    f16* W2T = (f16*)(base + 8 * MiB);    // [1024, 4096]
    f16* PWT = (f16*)(base + 16 * MiB);   // [4096, 1024] = [Wq|Wk|Wv|Wg]^T
    f16* WoT = (f16*)(base + 24 * MiB);   // [1024, 1024]
    f16* WaT = (f16*)(base + 26 * MiB);   // [2048, 1024]
    float4* chunk = (float4*)(base + 30 * MiB);
    float2* carry = (float2*)(base + 34 * MiB);
    float*  stats = (float*)(base + 36 * MiB);
    f16* xb  = (f16*)(base + 37 * MiB);   // [M,1024] fp16 = 32 MiB
    f16* P   = (f16*)(base + 69 * MiB);   // [M,4096] fp16 = 128 MiB, ends 197
    // aliases (lifetimes verified):
    f16*   ab = (f16*)d_out;              // [M,2048] fp16 = 64 MiB; dead after pass3
    f16*   yo = (f16*)d_out;              // Wo out [M,1024] f16; a dead by then
    f16*   x1 = xb;                       // post-ln1; xb dead after projections
    f16*   h1 = P;                        // [M,F] f16 = 128 MiB; P dead after Wo
    float* h2 = (float*)d_out;            // fp32 [M,D]; yo dead after ln1

    dim3 blk(256);
    dim3 gblk(512);

    // 0. conversions (PWT rows: 0 q | 1024 k | 2048 v | 3072 g)
    f2h_k<<<Mrows, blk, 0, stream>>>(x, xb);
    wtrans_k<<<dim3(128, 32), blk, 0, stream>>>(W1, W1T, Dd, Ff);
    wtrans_k<<<dim3(32, 128), blk, 0, stream>>>(W2, W2T, Ff, Dd);
    wtrans_k<<<dim3(32, 32),  blk, 0, stream>>>(Wq, PWT + 0u * 1048576, Dd, Dd);
    wtrans_k<<<dim3(32, 32),  blk, 0, stream>>>(Wk, PWT + 1u * 1048576, Dd, Dd);
    wtrans_k<<<dim3(32, 32),  blk, 0, stream>>>(Wv, PWT + 2u * 1048576, Dd, Dd);
    wtrans_k<<<dim3(32, 32),  blk, 0, stream>>>(Wg, PWT + 3u * 1048576, Dd, Dd);
    wtrans_k<<<dim3(32, 32),  blk, 0, stream>>>(Wo, WoT, Dd, Dd);
    wtrans_k<<<dim3(64, 32),  blk, 0, stream>>>(Wa, WaT, Dd, 2 * Dd);

    // 1. projections: one N=4096 GEMM (q|k|v|g) + one N=2048 (a)
    mgemm_k<0, f16><<<dim3(16, 128), gblk, 0, stream>>>(xb, Dd, PWT, P, PLD, Mrows, 4096, Dd, nullptr);
    mgemm_k<0, f16><<<dim3(8, 128),  gblk, 0, stream>>>(xb, Dd, WaT, ab, 2048, Mrows, 2048, Dd, nullptr);

    // 2. a transform (fp16, in place in d_out)
    a_transform_k<<<MD / (256 * 8), blk, 0, stream>>>(ab);

    // 3. chunked scan (k*v inline; y in-place over q cols of P)
    scan_pass1_k<<<CBD / 256, blk, 0, stream>>>(ab, P, chunk);
    scan_pass2_k<<<BD / 256, blk, 0, stream>>>(chunk, carry, stats);
    scan_pass3_k<<<CBD / 256, blk, 0, stream>>>(ab, P, carry, stats);

    // 4. groupnorm + silu(g) gate (in place on y cols of P)
    gn_gate_k<<<MD / (256 * 8), blk, 0, stream>>>(P, stats, gn_scale, gn_bias);

    // 5. output projection (A = y cols of P, lda=PLD) + ln1
    mgemm_k<0, f16><<<dim3(4, 128), gblk, 0, stream>>>(P, PLD, WoT, yo, Dd, Mrows, Dd, Dd, nullptr);
    ln_k<float, f16, f16><<<Mrows, blk, 0, stream>>>(x, yo, ln1_s, ln1_b, x1);

    // 6. MLP (h1 overlays P; h2 -> d_out fp32)
    mgemm_k<1, f16  ><<<dim3(16, 128), gblk, 0, stream>>>(x1, Dd, W1T, h1, Ff, Mrows, Ff, Dd, b1);
    mgemm_k<2, float><<<dim3(4, 128),  gblk, 0, stream>>>(h1, Ff, W2T, h2, Dd, Mrows, Dd, Ff, b2);

    // 7. final layernorm -> out (in place over h2: per-thread read-then-write)
    ln_k<f16, float, float><<<Mrows, blk, 0, stream>>>(x1, h2, ln2_s, ln2_b, out);
}

// Round 4
// 979.042 us; speedup vs baseline: 1.3929x; 1.3929x over previous
//
#include <hip/hip_runtime.h>
#include <cstdint>
#include <cstddef>

// ---------------------------------------------------------------------------
// GateLoop block, round 9: fix r8's register-clamp spills.
//   r8's launch_bounds(512,4) capped waves at 128 regs on the UNIFIED
//   VGPR/AGPR file: acc=64 AGPR left only 64 VGPRs -> loop-carried scratch
//   spills (WRITE_SIZE 445MB vs 134 ideal, FETCH +215MB, MFMA/VALU ~20%).
//   Fix: launch_bounds(512,2) (256-reg budget, no spills). LDS now caps
//   residency at 1 block/CU (2 waves/SIMD, m201's regime), so the pipeline
//   is deepened to cover latency: 4 LDS buffers (96 KiB), prefetch
//   distance 3, steady-state s_waitcnt vmcnt(6) (tail 3 -> 0), loop
//   unrolled x4 for static buffer indices (rule #20).
//   Protocol (proven correct in r8): per phase
//     ds_read(buf t%4) -> stage(t+3 -> buf (t+3)%4) -> vmcnt(6) ->
//     s_barrier (publishes tile t+1) -> setprio(1) 16 MFMA setprio(0) ->
//     s_barrier (write-after-read guard for recycled buffer)
//   Carried: 128x256 tile, 8 waves 64x64, chunk-XOR LDS swizzle (0 bank
//   conflicts), XCD-chunked block swizzle, fast gelu/sigmoid, consolidated
//   projections, vectorized pointwise kernels.
//
// Pipeline:
//   0. x -> fp16; weights -> transposed fp16 [N,K] (qkvg stacked)
//   1. mgemm x@[Wq|Wk|Wv|Wg] -> P[M,4096]; x@Wa -> ab (d_out)
//   2. a_transform in place (fp16, d_out)
//   3. chunked scan (3 passes, fp32 state); k*v inline;
//      pass3 writes y in-place over P's q columns
//   4. gn_gate + silu(g) (vectorized, in place on y cols of P)
//   5. mgemm y@Wo -> yo (d_out); ln1 -> x1 (xb slot)
//   6. mgemm x1@W1(+b1,fast gelu) -> h1 (overlays P); h1@W2(+b2) -> h2 (d_out)
//   7. ln2(x1 + h2) -> out (in place over h2)
//
// ws layout (MiB): 0 W1T(8) | 8 W2T(8) | 16 PWT(8) | 24 WoT(2) | 26 WaT(4) |
//   30 chunk(4) | 34 carry(2) | 36 stats | 37 xb(32) | 69 P(128) | 197 end.
// Aliases: ab & yo & h2 -> d_out; y over P q-cols; h1 -> P; x1 -> xb.
// ---------------------------------------------------------------------------

#define EPSN 1e-6f

typedef _Float16 f16;
typedef _Float16 f16x8 __attribute__((ext_vector_type(8)));
typedef _Float16 f16x4 __attribute__((ext_vector_type(4)));
typedef float    f32x4 __attribute__((ext_vector_type(4)));

static constexpr int    Bb     = 4;
static constexpr int    Ss     = 4096;
static constexpr int    Dd     = 1024;
static constexpr int    Ff     = 4096;
static constexpr int    Mrows  = Bb * Ss;                  // 16384
static constexpr size_t MD     = (size_t)Mrows * Dd;       // 16777216
static constexpr int    CHUNKS = 64;
static constexpr int    CLEN   = Ss / CHUNKS;              // 64
static constexpr int    BD     = Bb * Dd;                  // 4096
static constexpr int    CBD    = CHUNKS * BD;              // 262144
static constexpr size_t MiB    = 1024 * 1024;
static constexpr int    PLD    = 4096;                     // P row stride

__device__ __forceinline__ float fast_sigmoid(float x) {
    float e = __builtin_amdgcn_exp2f(-1.4426950408889634f * x);
    return __builtin_amdgcn_rcpf(1.0f + e);
}
__device__ __forceinline__ float gelu_tanh(float x) {
    float z = 0.7978845608028654f * (x + 0.044715f * x * x * x);
    z = fminf(fmaxf(z, -10.0f), 10.0f);          // tanh(+-10)=+-1 to fp32
    float e = __builtin_amdgcn_exp2f(2.885390081777927f * z);   // e^{2z}
    float t = (e - 1.0f) * __builtin_amdgcn_rcpf(e + 1.0f);
    return 0.5f * x * (1.0f + t);
}

// async global->LDS, 16 B per lane; lds dest = base + lane*16 (wave-uniform base)
__device__ __forceinline__ void async16(const void* g, void* l) {
    __builtin_amdgcn_global_load_lds(
        (const __attribute__((address_space(1))) unsigned int*)(uintptr_t)g,
        (__attribute__((address_space(3))) unsigned int*)(uintptr_t)l,
        16, 0, 0);
}

// ------- MFMA GEMM: C[M,N](ldc) = A[M,K](lda,f16) @ Bt[N,K](f16)^T ----------
// Tile 128x256, BK=32, 8 waves of 64x64, 4-buffer counted-vmcnt pipeline.
// EPI: 0 none | 1 bias+gelu | 2 bias
template <int EPI, typename TC>
__global__ __launch_bounds__(512, 2) void mgemm_k(const f16* __restrict__ A, int lda,
                                                  const f16* __restrict__ Bt,
                                                  TC* __restrict__ C, int ldc,
                                                  int M, int N, int K,
                                                  const float* __restrict__ bias) {
    __shared__ f16 sA[4][128 * 32];   // 8 KiB / buffer
    __shared__ f16 sB[4][256 * 32];   // 16 KiB / buffer  -> 96 KiB total
    const int tid  = threadIdx.x;
    const int wave = tid >> 6;        // 0..7
    const int lane = tid & 63;

    // XCD-chunked bijective swizzle (all grids have nwg % 8 == 0)
    const int gx  = gridDim.x;
    const int nwg = gx * gridDim.y;
    int bid = blockIdx.y * gx + blockIdx.x;
    bid = (bid & 7) * (nwg >> 3) + (bid >> 3);
    const int bm = (bid / gx) * 128;
    const int bn = (bid % gx) * 256;

    const int rw = (wave >> 2) * 64;  // wave row offset in tile (0,64)
    const int cw = (wave & 3) * 64;   // wave col offset in tile (0..192)

    // staging swizzle (r7-proven): lane l owns LDS (row16=l>>2, chunk=l&3);
    // fetches global chunk (l&3)^((l>>3)&3)
    const int swzc = (((lane & 3) ^ (lane >> 3)) & 3) * 8;
    // wave w stages: A rows [w*16,+16) | B rows [w*16,..) | B rows [128+w*16,..)
    const f16* gS0 = A  + (size_t)(bm + wave * 16 + (lane >> 2)) * lda + swzc;
    const f16* gS1 = Bt + (size_t)(bn + wave * 16 + (lane >> 2)) * K   + swzc;
    const f16* gS2 = Bt + (size_t)(bn + 128 + wave * 16 + (lane >> 2)) * K + swzc;

    f32x4 acc[4][4] = {};

    // fragment read swizzle (r7-proven)
    const int fr  = lane & 15;
    const int fco = (((lane >> 4) ^ (lane >> 1)) & 3) * 8;

    const int NT = K >> 5;            // K-tiles of 32; NT % 4 == 0 (K 1024/4096)

    // prologue: stage tiles 0,1,2; drain tile 0 (leave 6 = tiles 1,2); publish
    async16(gS0,      &sA[0][wave * 512]);
    async16(gS1,      &sB[0][wave * 512]);
    async16(gS2,      &sB[0][(8 + wave) * 512]);
    async16(gS0 + 32, &sA[1][wave * 512]);
    async16(gS1 + 32, &sB[1][wave * 512]);
    async16(gS2 + 32, &sB[1][(8 + wave) * 512]);
    async16(gS0 + 64, &sA[2][wave * 512]);
    async16(gS1 + 64, &sB[2][wave * 512]);
    async16(gS2 + 64, &sB[2][(8 + wave) * 512]);
    asm volatile("s_waitcnt vmcnt(6)" ::: "memory");
    __builtin_amdgcn_s_barrier();

#define MG_PHASE(T, BR)                                                        \
    {                                                                          \
        const int t_ = (T);                                                    \
        f16x8 af[4], bfr[4];                                                   \
        _Pragma("unroll") for (int i = 0; i < 4; ++i)                          \
            af[i] = *(const f16x8*)&sA[BR][(rw + i * 16 + fr) * 32 + fco];     \
        _Pragma("unroll") for (int j = 0; j < 4; ++j)                          \
            bfr[j] = *(const f16x8*)&sB[BR][(cw + j * 16 + fr) * 32 + fco];    \
        if (t_ + 3 < NT) {                                                     \
            const int kk = (t_ + 3) * 32;                                      \
            async16(gS0 + kk, &sA[(BR + 3) & 3][wave * 512]);                  \
            async16(gS1 + kk, &sB[(BR + 3) & 3][wave * 512]);                  \
            async16(gS2 + kk, &sB[(BR + 3) & 3][(8 + wave) * 512]);            \
            asm volatile("s_waitcnt vmcnt(6)" ::: "memory");                   \
        } else if (t_ + 2 < NT) {                                              \
            asm volatile("s_waitcnt vmcnt(3)" ::: "memory");                   \
        } else {                                                               \
            asm volatile("s_waitcnt vmcnt(0)" ::: "memory");                   \
        }                                                                      \
        __builtin_amdgcn_s_barrier();                                          \
        __builtin_amdgcn_s_setprio(1);                                         \
        _Pragma("unroll") for (int i = 0; i < 4; ++i)                          \
            _Pragma("unroll") for (int j = 0; j < 4; ++j)                      \
                acc[i][j] = __builtin_amdgcn_mfma_f32_16x16x32_f16(            \
                    af[i], bfr[j], acc[i][j], 0, 0, 0);                        \
        __builtin_amdgcn_s_setprio(0);                                         \
        __builtin_amdgcn_s_barrier();                                          \
    }

    for (int t = 0; t + 4 <= NT; t += 4) {
        MG_PHASE(t,     0)
        MG_PHASE(t + 1, 1)
        MG_PHASE(t + 2, 2)
        MG_PHASE(t + 3, 3)
    }
#undef MG_PHASE

    // epilogue: C row = (lane>>4)*4 + reg, col = lane&15  (dtype-independent)
    const int er = (lane >> 4) * 4;
    const int ec = lane & 15;
#pragma unroll
    for (int i = 0; i < 4; ++i) {
#pragma unroll
        for (int j = 0; j < 4; ++j) {
            const int col = bn + cw + j * 16 + ec;
#pragma unroll
            for (int r = 0; r < 4; ++r) {
                const size_t row = (size_t)(bm + rw + i * 16 + er + r);
                float o = acc[i][j][r];
                if (EPI == 1 || EPI == 2) o += bias[col];
                if (EPI == 1) o = gelu_tanh(o);
                if (sizeof(TC) == 4) ((float*)C)[row * ldc + col] = o;
                else                 ((f16*)C)[row * ldc + col] = (f16)o;
            }
        }
    }
}

// ---------------- weight transpose+convert: Wt[n][k] = f16(W[k][n]) ---------
__global__ __launch_bounds__(256) void wtrans_k(const float* __restrict__ W,
                                                f16* __restrict__ Wt,
                                                int K, int N) {
    __shared__ float t[32][33];
    const int n0 = blockIdx.x * 32, k0 = blockIdx.y * 32;
    const int tx = threadIdx.x & 31, ty = threadIdx.x >> 5;   // 8 rows
#pragma unroll
    for (int i = 0; i < 32; i += 8)
        t[ty + i][tx] = W[(size_t)(k0 + ty + i) * N + n0 + tx];
    __syncthreads();
#pragma unroll
    for (int i = 0; i < 32; i += 8)
        Wt[(size_t)(n0 + ty + i) * K + k0 + tx] = (f16)t[tx][ty + i];
}

// ---------------- x fp32 -> fp16 --------------------------------------------
__global__ __launch_bounds__(256) void f2h_k(const float* __restrict__ x,
                                             f16* __restrict__ xh) {
    size_t i = ((size_t)blockIdx.x * 256 + threadIdx.x) * 4;
    float4 v = *(const float4*)&x[i];
    f16x4 s;
    s.x = (f16)v.x; s.y = (f16)v.y; s.z = (f16)v.z; s.w = (f16)v.w;
    *(f16x4*)&xh[i] = s;
}

// ------- a transform: a_c = sigmoid(|a|)*a/|a| (fp16 in place, x8) ----------
__global__ __launch_bounds__(256) void a_transform_k(f16* __restrict__ a2d) {
    size_t gid = (size_t)blockIdx.x * 256 + threadIdx.x;   // < M*D/8
    int    j8  = (int)(gid & 127) * 8;
    size_t row = gid >> 7;
    f16x8 vr = *(f16x8*)&a2d[row * 2048 + j8];
    f16x8 vi = *(f16x8*)&a2d[row * 2048 + 1024 + j8];
#pragma unroll
    for (int i = 0; i < 8; ++i) {
        float ar = (float)vr[i], ai = (float)vi[i];
        float mag = sqrtf(ar * ar + ai * ai);
        float sg  = fast_sigmoid(mag);
        float re, im;
        if (mag > 1e-30f) { float s = sg * __builtin_amdgcn_rcpf(mag); re = ar * s; im = ai * s; }
        else              { re = sg; im = 0.0f; }
        vr[i] = (f16)re; vi[i] = (f16)im;
    }
    *(f16x8*)&a2d[row * 2048 + j8]        = vr;
    *(f16x8*)&a2d[row * 2048 + 1024 + j8] = vi;
}

// ---------------- chunked complex scan (fp32 state) -------------------------
// P columns: q 0..1023 | k 1024..2047 | v 2048..3071 | g 3072..4095
__global__ __launch_bounds__(256) void scan_pass1_k(const f16* __restrict__ a2d,
                                                    const f16* __restrict__ P,
                                                    float4* __restrict__ chunk) {
    int tid = blockIdx.x * 256 + threadIdx.x;    // < CBD
    int d   = tid & 1023;
    int t1  = tid >> 10;
    int b   = t1 & 3;
    int c   = t1 >> 2;
    int t0  = c * CLEN;
    int rbase = b * Ss;
    float Are = 1.0f, Aim = 0.0f, Hre = 0.0f, Him = 0.0f;
    for (int t = t0; t < t0 + CLEN; ++t) {
        int r = rbase + t;
        float are = (float)a2d[(size_t)r * 2048 + d];
        float aim = (float)a2d[(size_t)r * 2048 + 1024 + d];
        float kvv = (float)P[(size_t)r * PLD + 1024 + d]
                  * (float)P[(size_t)r * PLD + 2048 + d];
        float hre = are * Hre - aim * Him + kvv;
        float him = are * Him + aim * Hre;
        Hre = hre; Him = him;
        float pre = are * Are - aim * Aim;
        float pim = are * Aim + aim * Are;
        Are = pre; Aim = pim;
    }
    chunk[tid] = make_float4(Are, Aim, Hre, Him);
}

__global__ __launch_bounds__(256) void scan_pass2_k(const float4* __restrict__ chunk,
                                                    float2* __restrict__ carry,
                                                    float* __restrict__ stats) {
    int tid = blockIdx.x * blockDim.x + threadIdx.x;  // < B*D = 4096
    if (tid < 512) stats[tid] = 0.0f;                 // ws is poisoned: zero gn stats
    float hre = 0.0f, him = 0.0f;
    for (int c = 0; c < CHUNKS; ++c) {
        int task = c * BD + tid;
        float4 ch = chunk[task];
        carry[task] = make_float2(hre, him);
        float nre = ch.x * hre - ch.y * him + ch.z;
        float nim = ch.x * him + ch.y * hre + ch.w;
        hre = nre; him = nim;
    }
}

// pass3: y written in place over P's q columns (per-elem read-then-write)
__global__ __launch_bounds__(256) void scan_pass3_k(const f16* __restrict__ a2d,
                                                    f16* __restrict__ P,
                                                    const float2* __restrict__ carry,
                                                    float* __restrict__ stats) {
    int tid = blockIdx.x * 256 + threadIdx.x;    // < CBD
    int d   = tid & 1023;
    int t1  = tid >> 10;
    int b   = t1 & 3;
    int c   = t1 >> 2;
    int t0  = c * CLEN;
    int rbase = b * Ss;
    float2 cr = carry[tid];
    float hre = cr.x, him = cr.y;
    float sre = 0.0f, sim = 0.0f, s2 = 0.0f;
    for (int t = t0; t < t0 + CLEN; ++t) {
        int r = rbase + t;
        float are = (float)a2d[(size_t)r * 2048 + d];
        float aim = (float)a2d[(size_t)r * 2048 + 1024 + d];
        float kvv = (float)P[(size_t)r * PLD + 1024 + d]
                  * (float)P[(size_t)r * PLD + 2048 + d];
        float nre = are * hre - aim * him + kvv;
        float nim = are * him + aim * hre;
        hre = nre; him = nim;
        float qv  = (float)P[(size_t)r * PLD + d];
        float yr_ = qv * hre;
        float yi_ = qv * him;
        P[(size_t)r * PLD + d] = (f16)yr_;       // overwrite q with y (safe)
        sre += yr_; sim += yi_; s2 += yr_ * yr_ + yi_ * yi_;
    }
#pragma unroll
    for (int off = 16; off > 0; off >>= 1) {
        sre += __shfl_down(sre, off, 32);
        sim += __shfl_down(sim, off, 32);
        s2  += __shfl_down(s2,  off, 32);
    }
    if ((threadIdx.x & 31) == 0) {
        int idx = (b * 32 + (d >> 5)) * 4;
        atomicAdd(&stats[idx + 0], sre);
        atomicAdd(&stats[idx + 1], sim);
        atomicAdd(&stats[idx + 2], s2);
    }
}

// ------- groupnorm (real) + silu(g)-gate, f16x8, in place on y cols ---------
__global__ __launch_bounds__(256) void gn_gate_k(f16* __restrict__ P,
                                                 const float* __restrict__ stats,
                                                 const float* __restrict__ gn_scale,
                                                 const float* __restrict__ gn_bias) {
    size_t gid = (size_t)blockIdx.x * 256 + threadIdx.x;  // < M*D/8
    int d8  = (int)(gid & 127) * 8;
    int row = (int)(gid >> 7);
    int b   = row >> 12;
    int grp = d8 >> 5;
    const float* st = &stats[(b * 32 + grp) * 4];
    const float invN = 1.0f / 131072.0f;       // S * (D/G)
    float mre = st[0] * invN;
    float mim = st[1] * invN;
    float var = st[2] * invN - mre * mre - mim * mim;
    float rstd = rsqrtf(var + EPSN);
    f16x8 yv = *(f16x8*)&P[(size_t)row * PLD + d8];
    f16x8 gv = *(const f16x8*)&P[(size_t)row * PLD + 3072 + d8];
#pragma unroll
    for (int i = 0; i < 8; ++i) {
        float re = ((float)yv[i] - mre) * rstd * gn_scale[d8 + i] + gn_bias[d8 + i];
        float gx = (float)gv[i];
        yv[i] = (f16)(re * gx * fast_sigmoid(gx));
    }
    *(f16x8*)&P[(size_t)row * PLD + d8] = yv;
}

// ---------------- layernorm over D=1024: out = LN(a + b) --------------------
__device__ __forceinline__ float ldf(const float* p, size_t i) { return p[i]; }
__device__ __forceinline__ float ldf(const f16* p, size_t i)   { return (float)p[i]; }
__device__ __forceinline__ void  stf(float* p, size_t i, float v) { p[i] = v; }
__device__ __forceinline__ void  stf(f16* p, size_t i, float v)   { p[i] = (f16)v; }

__device__ __forceinline__ float block_reduce_sum(float v, float* s4, int tid) {
#pragma unroll
    for (int off = 32; off > 0; off >>= 1) v += __shfl_down(v, off, 64);
    __syncthreads();
    if ((tid & 63) == 0) s4[tid >> 6] = v;
    __syncthreads();
    return s4[0] + s4[1] + s4[2] + s4[3];
}

template <typename TA, typename TB, typename TO>
__global__ __launch_bounds__(256) void ln_k(const TA* __restrict__ a,
                                            const TB* __restrict__ b,
                                            const float* __restrict__ scale,
                                            const float* __restrict__ bias,
                                            TO* __restrict__ out) {
    __shared__ float s4[4];
    int row = blockIdx.x;
    size_t base = (size_t)row * 1024;
    int tid = threadIdx.x;
    float v[4];
    float s = 0.0f;
#pragma unroll
    for (int i = 0; i < 4; ++i) {
        int d = tid + i * 256;
        v[i] = ldf(a, base + d) + ldf(b, base + d);
        s += v[i];
    }
    float mu = block_reduce_sum(s, s4, tid) * (1.0f / 1024.0f);
    float s2 = 0.0f;
#pragma unroll
    for (int i = 0; i < 4; ++i) {
        float dv = v[i] - mu;
        s2 += dv * dv;
    }
    float var = block_reduce_sum(s2, s4, tid) * (1.0f / 1024.0f);
    float rstd = rsqrtf(var + EPSN);
#pragma unroll
    for (int i = 0; i < 4; ++i) {
        int d = tid + i * 256;
        stf(out, base + d, (v[i] - mu) * rstd * scale[d] + bias[d]);
    }
}

// ---------------------------------------------------------------------------
extern "C" void kernel_launch(void* const* d_in, const int* in_sizes, int n_in,
                              void* d_out, int out_size, void* d_ws, size_t ws_size,
                              hipStream_t stream) {
    const float* x        = (const float*)d_in[0];
    const float* Wq       = (const float*)d_in[1];
    const float* Wk       = (const float*)d_in[2];
    const float* Wv       = (const float*)d_in[3];
    const float* Wa       = (const float*)d_in[4];
    const float* Wg       = (const float*)d_in[5];
    const float* Wo       = (const float*)d_in[6];
    const float* gn_scale = (const float*)d_in[7];
    const float* gn_bias  = (const float*)d_in[8];
    const float* ln1_s    = (const float*)d_in[9];
    const float* ln1_b    = (const float*)d_in[10];
    const float* W1       = (const float*)d_in[11];
    const float* b1       = (const float*)d_in[12];
    const float* W2       = (const float*)d_in[13];
    const float* b2       = (const float*)d_in[14];
    const float* ln2_s    = (const float*)d_in[15];
    const float* ln2_b    = (const float*)d_in[16];
    float* out = (float*)d_out;

    char* base = (char*)d_ws;
    f16* W1T = (f16*)(base + 0 * MiB);    // [4096, 1024]
    f16* W2T = (f16*)(base + 8 * MiB);    // [1024, 4096]
    f16* PWT = (f16*)(base + 16 * MiB);   // [4096, 1024] = [Wq|Wk|Wv|Wg]^T
    f16* WoT = (f16*)(base + 24 * MiB);   // [1024, 1024]
    f16* WaT = (f16*)(base + 26 * MiB);   // [2048, 1024]
    float4* chunk = (float4*)(base + 30 * MiB);
    float2* carry = (float2*)(base + 34 * MiB);
    float*  stats = (float*)(base + 36 * MiB);
    f16* xb  = (f16*)(base + 37 * MiB);   // [M,1024] fp16 = 32 MiB
    f16* P   = (f16*)(base + 69 * MiB);   // [M,4096] fp16 = 128 MiB, ends 197
    // aliases (lifetimes verified):
    f16*   ab = (f16*)d_out;              // [M,2048] fp16 = 64 MiB; dead after pass3
    f16*   yo = (f16*)d_out;              // Wo out [M,1024] f16; a dead by then
    f16*   x1 = xb;                       // post-ln1; xb dead after projections
    f16*   h1 = P;                        // [M,F] f16 = 128 MiB; P dead after Wo
    float* h2 = (float*)d_out;            // fp32 [M,D]; yo dead after ln1

    dim3 blk(256);
    dim3 gblk(512);

    // 0. conversions (PWT rows: 0 q | 1024 k | 2048 v | 3072 g)
    f2h_k<<<Mrows, blk, 0, stream>>>(x, xb);
    wtrans_k<<<dim3(128, 32), blk, 0, stream>>>(W1, W1T, Dd, Ff);
    wtrans_k<<<dim3(32, 128), blk, 0, stream>>>(W2, W2T, Ff, Dd);
    wtrans_k<<<dim3(32, 32),  blk, 0, stream>>>(Wq, PWT + 0u * 1048576, Dd, Dd);
    wtrans_k<<<dim3(32, 32),  blk, 0, stream>>>(Wk, PWT + 1u * 1048576, Dd, Dd);
    wtrans_k<<<dim3(32, 32),  blk, 0, stream>>>(Wv, PWT + 2u * 1048576, Dd, Dd);
    wtrans_k<<<dim3(32, 32),  blk, 0, stream>>>(Wg, PWT + 3u * 1048576, Dd, Dd);
    wtrans_k<<<dim3(32, 32),  blk, 0, stream>>>(Wo, WoT, Dd, Dd);
    wtrans_k<<<dim3(64, 32),  blk, 0, stream>>>(Wa, WaT, Dd, 2 * Dd);

    // 1. projections: one N=4096 GEMM (q|k|v|g) + one N=2048 (a)
    mgemm_k<0, f16><<<dim3(16, 128), gblk, 0, stream>>>(xb, Dd, PWT, P, PLD, Mrows, 4096, Dd, nullptr);
    mgemm_k<0, f16><<<dim3(8, 128),  gblk, 0, stream>>>(xb, Dd, WaT, ab, 2048, Mrows, 2048, Dd, nullptr);

    // 2. a transform (fp16, in place in d_out)
    a_transform_k<<<MD / (256 * 8), blk, 0, stream>>>(ab);

    // 3. chunked scan (k*v inline; y in-place over q cols of P)
    scan_pass1_k<<<CBD / 256, blk, 0, stream>>>(ab, P, chunk);
    scan_pass2_k<<<BD / 256, blk, 0, stream>>>(chunk, carry, stats);
    scan_pass3_k<<<CBD / 256, blk, 0, stream>>>(ab, P, carry, stats);

    // 4. groupnorm + silu(g) gate (in place on y cols of P)
    gn_gate_k<<<MD / (256 * 8), blk, 0, stream>>>(P, stats, gn_scale, gn_bias);

    // 5. output projection (A = y cols of P, lda=PLD) + ln1
    mgemm_k<0, f16><<<dim3(4, 128), gblk, 0, stream>>>(P, PLD, WoT, yo, Dd, Mrows, Dd, Dd, nullptr);
    ln_k<float, f16, f16><<<Mrows, blk, 0, stream>>>(x, yo, ln1_s, ln1_b, x1);

    // 6. MLP (h1 overlays P; h2 -> d_out fp32)
    mgemm_k<1, f16  ><<<dim3(16, 128), gblk, 0, stream>>>(x1, Dd, W1T, h1, Ff, Mrows, Ff, Dd, b1);
    mgemm_k<2, float><<<dim3(4, 128),  gblk, 0, stream>>>(h1, Ff, W2T, h2, Dd, Mrows, Dd, Ff, b2);

    // 7. final layernorm -> out (in place over h2: per-thread read-then-write)
    ln_k<f16, float, float><<<Mrows, blk, 0, stream>>>(x1, h2, ln2_s, ln2_b, out);
}

// Round 5
// 918.891 us; speedup vs baseline: 1.4841x; 1.0655x over previous
//
#include <hip/hip_runtime.h>
#include <cstdint>
#include <cstddef>

// ---------------------------------------------------------------------------
// GateLoop block, round 10: deepen per-wave tile (fix LDS-BW-bound GEMM).
//   r9's 64x64/wave (acc 4x4) gave 32 FLOP per LDS byte: per phase 64 KiB
//   LDS reads (~256cy) vs ~155cy MFMA -> LDS-read-bound, MfmaUtil 28%.
//   r10: BM=BN=256, 8 waves of 128x64 (acc 8x4): per phase 12 ds_read
//   feed 32 MFMA (42.7 FLOP/B), phase overhead amortized over 2x MFMA.
//   Sync protocol UNCHANGED from r9 (proven 2 rounds): 4 LDS buffers
//   (32 KiB each, 128 KiB), prefetch distance 3, counted vmcnt
//   (8 = 2 tiles x 4 loads/tile; tail 4 -> 0), raw s_barrier pair,
//   setprio(1) around MFMA cluster, x4-unrolled static buffer indices.
//   Chunk-XOR swizzle byte-identical (0 bank conflicts measured).
//   Regs: acc 128 + af 32 + bf 16 + addr ~25 => ~200 < 256 budget at
//   launch_bounds(512,2) -- no spills (r8 lesson).
//   Carried: XCD-chunked block swizzle, fast gelu/sigmoid, consolidated
//   projections, vectorized pointwise kernels.
//
// Pipeline:
//   0. x -> fp16; weights -> transposed fp16 [N,K] (qkvg stacked)
//   1. mgemm x@[Wq|Wk|Wv|Wg] -> P[M,4096]; x@Wa -> ab (d_out)
//   2. a_transform in place (fp16, d_out)
//   3. chunked scan (3 passes, fp32 state); k*v inline;
//      pass3 writes y in-place over P's q columns
//   4. gn_gate + silu(g) (vectorized, in place on y cols of P)
//   5. mgemm y@Wo -> yo (d_out); ln1 -> x1 (xb slot)
//   6. mgemm x1@W1(+b1,fast gelu) -> h1 (overlays P); h1@W2(+b2) -> h2 (d_out)
//   7. ln2(x1 + h2) -> out (in place over h2)
//
// ws layout (MiB): 0 W1T(8) | 8 W2T(8) | 16 PWT(8) | 24 WoT(2) | 26 WaT(4) |
//   30 chunk(4) | 34 carry(2) | 36 stats | 37 xb(32) | 69 P(128) | 197 end.
// Aliases: ab & yo & h2 -> d_out; y over P q-cols; h1 -> P; x1 -> xb.
// ---------------------------------------------------------------------------

#define EPSN 1e-6f

typedef _Float16 f16;
typedef _Float16 f16x8 __attribute__((ext_vector_type(8)));
typedef _Float16 f16x4 __attribute__((ext_vector_type(4)));
typedef float    f32x4 __attribute__((ext_vector_type(4)));

static constexpr int    Bb     = 4;
static constexpr int    Ss     = 4096;
static constexpr int    Dd     = 1024;
static constexpr int    Ff     = 4096;
static constexpr int    Mrows  = Bb * Ss;                  // 16384
static constexpr size_t MD     = (size_t)Mrows * Dd;       // 16777216
static constexpr int    CHUNKS = 64;
static constexpr int    CLEN   = Ss / CHUNKS;              // 64
static constexpr int    BD     = Bb * Dd;                  // 4096
static constexpr int    CBD    = CHUNKS * BD;              // 262144
static constexpr size_t MiB    = 1024 * 1024;
static constexpr int    PLD    = 4096;                     // P row stride

__device__ __forceinline__ float fast_sigmoid(float x) {
    float e = __builtin_amdgcn_exp2f(-1.4426950408889634f * x);
    return __builtin_amdgcn_rcpf(1.0f + e);
}
__device__ __forceinline__ float gelu_tanh(float x) {
    float z = 0.7978845608028654f * (x + 0.044715f * x * x * x);
    z = fminf(fmaxf(z, -10.0f), 10.0f);          // tanh(+-10)=+-1 to fp32
    float e = __builtin_amdgcn_exp2f(2.885390081777927f * z);   // e^{2z}
    float t = (e - 1.0f) * __builtin_amdgcn_rcpf(e + 1.0f);
    return 0.5f * x * (1.0f + t);
}

// async global->LDS, 16 B per lane; lds dest = base + lane*16 (wave-uniform base)
__device__ __forceinline__ void async16(const void* g, void* l) {
    __builtin_amdgcn_global_load_lds(
        (const __attribute__((address_space(1))) unsigned int*)(uintptr_t)g,
        (__attribute__((address_space(3))) unsigned int*)(uintptr_t)l,
        16, 0, 0);
}

// ------- MFMA GEMM: C[M,N](ldc) = A[M,K](lda,f16) @ Bt[N,K](f16)^T ----------
// Tile 256x256, BK=32, 8 waves of 128x64 (acc 8x4), 4-buffer counted-vmcnt
// pipeline. EPI: 0 none | 1 bias+gelu | 2 bias
template <int EPI, typename TC>
__global__ __launch_bounds__(512, 2) void mgemm_k(const f16* __restrict__ A, int lda,
                                                  const f16* __restrict__ Bt,
                                                  TC* __restrict__ C, int ldc,
                                                  int M, int N, int K,
                                                  const float* __restrict__ bias) {
    __shared__ f16 sA[4][256 * 32];   // 16 KiB / buffer
    __shared__ f16 sB[4][256 * 32];   // 16 KiB / buffer -> 128 KiB total
    const int tid  = threadIdx.x;
    const int wave = tid >> 6;        // 0..7
    const int lane = tid & 63;

    // XCD-chunked bijective swizzle (all grids have nwg % 8 == 0)
    const int gx  = gridDim.x;
    const int nwg = gx * gridDim.y;
    int bid = blockIdx.y * gx + blockIdx.x;
    bid = (bid & 7) * (nwg >> 3) + (bid >> 3);
    const int bm = (bid / gx) * 256;
    const int bn = (bid % gx) * 256;

    const int rw = (wave >> 2) * 128; // wave row offset (0 or 128)
    const int cw = (wave & 3) * 64;   // wave col offset (0..192)

    // staging swizzle (r7-proven): lane l owns LDS (row16 = l>>2, chunk = l&3);
    // fetches global chunk (l&3)^((l>>3)&3). Wave w stages rows [32w, 32w+32).
    const int swzc = (((lane & 3) ^ (lane >> 3)) & 3) * 8;
    const f16* gSA = A  + (size_t)(bm + wave * 32 + (lane >> 2)) * lda + swzc;
    const f16* gSB = Bt + (size_t)(bn + wave * 32 + (lane >> 2)) * K   + swzc;

    f32x4 acc[8][4] = {};

    // fragment read swizzle (r7-proven)
    const int fr  = lane & 15;
    const int fco = (((lane >> 4) ^ (lane >> 1)) & 3) * 8;

    const int NT = K >> 5;            // K-tiles of 32; NT % 4 == 0 (K 1024/4096)

#define MG_STAGE(BUF, KOFF)                                                    \
    {                                                                          \
        async16(gSA + (KOFF),                    &sA[BUF][wave * 1024]);       \
        async16(gSA + 16 * (size_t)lda + (KOFF), &sA[BUF][wave * 1024 + 512]); \
        async16(gSB + (KOFF),                    &sB[BUF][wave * 1024]);       \
        async16(gSB + 16 * (size_t)K + (KOFF),   &sB[BUF][wave * 1024 + 512]); \
    }

    // prologue: stage tiles 0,1,2; drain tile 0 (leave 8 = tiles 1,2); publish
    MG_STAGE(0, 0)
    MG_STAGE(1, 32)
    MG_STAGE(2, 64)
    asm volatile("s_waitcnt vmcnt(8)" ::: "memory");
    __builtin_amdgcn_s_barrier();

#define MG_PHASE(T, BR)                                                        \
    {                                                                          \
        const int t_ = (T);                                                    \
        f16x8 af[8], bf[4];                                                    \
        _Pragma("unroll") for (int i = 0; i < 8; ++i)                          \
            af[i] = *(const f16x8*)&sA[BR][(rw + i * 16 + fr) * 32 + fco];     \
        _Pragma("unroll") for (int j = 0; j < 4; ++j)                          \
            bf[j] = *(const f16x8*)&sB[BR][(cw + j * 16 + fr) * 32 + fco];     \
        if (t_ + 3 < NT) {                                                     \
            MG_STAGE((BR + 3) & 3, (t_ + 3) * 32)                              \
            asm volatile("s_waitcnt vmcnt(8)" ::: "memory");                   \
        } else if (t_ + 2 < NT) {                                              \
            asm volatile("s_waitcnt vmcnt(4)" ::: "memory");                   \
        } else {                                                               \
            asm volatile("s_waitcnt vmcnt(0)" ::: "memory");                   \
        }                                                                      \
        __builtin_amdgcn_s_barrier();                                          \
        __builtin_amdgcn_s_setprio(1);                                         \
        _Pragma("unroll") for (int i = 0; i < 8; ++i)                          \
            _Pragma("unroll") for (int j = 0; j < 4; ++j)                      \
                acc[i][j] = __builtin_amdgcn_mfma_f32_16x16x32_f16(            \
                    af[i], bf[j], acc[i][j], 0, 0, 0);                         \
        __builtin_amdgcn_s_setprio(0);                                         \
        __builtin_amdgcn_s_barrier();                                          \
    }

    for (int t = 0; t + 4 <= NT; t += 4) {
        MG_PHASE(t,     0)
        MG_PHASE(t + 1, 1)
        MG_PHASE(t + 2, 2)
        MG_PHASE(t + 3, 3)
    }
#undef MG_PHASE
#undef MG_STAGE

    // epilogue: C row = (lane>>4)*4 + reg, col = lane&15  (dtype-independent)
    const int er = (lane >> 4) * 4;
    const int ec = lane & 15;
#pragma unroll
    for (int i = 0; i < 8; ++i) {
#pragma unroll
        for (int j = 0; j < 4; ++j) {
            const int col = bn + cw + j * 16 + ec;
#pragma unroll
            for (int r = 0; r < 4; ++r) {
                const size_t row = (size_t)(bm + rw + i * 16 + er + r);
                float o = acc[i][j][r];
                if (EPI == 1 || EPI == 2) o += bias[col];
                if (EPI == 1) o = gelu_tanh(o);
                if (sizeof(TC) == 4) ((float*)C)[row * ldc + col] = o;
                else                 ((f16*)C)[row * ldc + col] = (f16)o;
            }
        }
    }
}

// ---------------- weight transpose+convert: Wt[n][k] = f16(W[k][n]) ---------
__global__ __launch_bounds__(256) void wtrans_k(const float* __restrict__ W,
                                                f16* __restrict__ Wt,
                                                int K, int N) {
    __shared__ float t[32][33];
    const int n0 = blockIdx.x * 32, k0 = blockIdx.y * 32;
    const int tx = threadIdx.x & 31, ty = threadIdx.x >> 5;   // 8 rows
#pragma unroll
    for (int i = 0; i < 32; i += 8)
        t[ty + i][tx] = W[(size_t)(k0 + ty + i) * N + n0 + tx];
    __syncthreads();
#pragma unroll
    for (int i = 0; i < 32; i += 8)
        Wt[(size_t)(n0 + ty + i) * K + k0 + tx] = (f16)t[tx][ty + i];
}

// ---------------- x fp32 -> fp16 --------------------------------------------
__global__ __launch_bounds__(256) void f2h_k(const float* __restrict__ x,
                                             f16* __restrict__ xh) {
    size_t i = ((size_t)blockIdx.x * 256 + threadIdx.x) * 4;
    float4 v = *(const float4*)&x[i];
    f16x4 s;
    s.x = (f16)v.x; s.y = (f16)v.y; s.z = (f16)v.z; s.w = (f16)v.w;
    *(f16x4*)&xh[i] = s;
}

// ------- a transform: a_c = sigmoid(|a|)*a/|a| (fp16 in place, x8) ----------
__global__ __launch_bounds__(256) void a_transform_k(f16* __restrict__ a2d) {
    size_t gid = (size_t)blockIdx.x * 256 + threadIdx.x;   // < M*D/8
    int    j8  = (int)(gid & 127) * 8;
    size_t row = gid >> 7;
    f16x8 vr = *(f16x8*)&a2d[row * 2048 + j8];
    f16x8 vi = *(f16x8*)&a2d[row * 2048 + 1024 + j8];
#pragma unroll
    for (int i = 0; i < 8; ++i) {
        float ar = (float)vr[i], ai = (float)vi[i];
        float mag = sqrtf(ar * ar + ai * ai);
        float sg  = fast_sigmoid(mag);
        float re, im;
        if (mag > 1e-30f) { float s = sg * __builtin_amdgcn_rcpf(mag); re = ar * s; im = ai * s; }
        else              { re = sg; im = 0.0f; }
        vr[i] = (f16)re; vi[i] = (f16)im;
    }
    *(f16x8*)&a2d[row * 2048 + j8]        = vr;
    *(f16x8*)&a2d[row * 2048 + 1024 + j8] = vi;
}

// ---------------- chunked complex scan (fp32 state) -------------------------
// P columns: q 0..1023 | k 1024..2047 | v 2048..3071 | g 3072..4095
__global__ __launch_bounds__(256) void scan_pass1_k(const f16* __restrict__ a2d,
                                                    const f16* __restrict__ P,
                                                    float4* __restrict__ chunk) {
    int tid = blockIdx.x * 256 + threadIdx.x;    // < CBD
    int d   = tid & 1023;
    int t1  = tid >> 10;
    int b   = t1 & 3;
    int c   = t1 >> 2;
    int t0  = c * CLEN;
    int rbase = b * Ss;
    float Are = 1.0f, Aim = 0.0f, Hre = 0.0f, Him = 0.0f;
    for (int t = t0; t < t0 + CLEN; ++t) {
        int r = rbase + t;
        float are = (float)a2d[(size_t)r * 2048 + d];
        float aim = (float)a2d[(size_t)r * 2048 + 1024 + d];
        float kvv = (float)P[(size_t)r * PLD + 1024 + d]
                  * (float)P[(size_t)r * PLD + 2048 + d];
        float hre = are * Hre - aim * Him + kvv;
        float him = are * Him + aim * Hre;
        Hre = hre; Him = him;
        float pre = are * Are - aim * Aim;
        float pim = are * Aim + aim * Are;
        Are = pre; Aim = pim;
    }
    chunk[tid] = make_float4(Are, Aim, Hre, Him);
}

__global__ __launch_bounds__(256) void scan_pass2_k(const float4* __restrict__ chunk,
                                                    float2* __restrict__ carry,
                                                    float* __restrict__ stats) {
    int tid = blockIdx.x * blockDim.x + threadIdx.x;  // < B*D = 4096
    if (tid < 512) stats[tid] = 0.0f;                 // ws is poisoned: zero gn stats
    float hre = 0.0f, him = 0.0f;
    for (int c = 0; c < CHUNKS; ++c) {
        int task = c * BD + tid;
        float4 ch = chunk[task];
        carry[task] = make_float2(hre, him);
        float nre = ch.x * hre - ch.y * him + ch.z;
        float nim = ch.x * him + ch.y * hre + ch.w;
        hre = nre; him = nim;
    }
}

// pass3: y written in place over P's q columns (per-elem read-then-write)
__global__ __launch_bounds__(256) void scan_pass3_k(const f16* __restrict__ a2d,
                                                    f16* __restrict__ P,
                                                    const float2* __restrict__ carry,
                                                    float* __restrict__ stats) {
    int tid = blockIdx.x * 256 + threadIdx.x;    // < CBD
    int d   = tid & 1023;
    int t1  = tid >> 10;
    int b   = t1 & 3;
    int c   = t1 >> 2;
    int t0  = c * CLEN;
    int rbase = b * Ss;
    float2 cr = carry[tid];
    float hre = cr.x, him = cr.y;
    float sre = 0.0f, sim = 0.0f, s2 = 0.0f;
    for (int t = t0; t < t0 + CLEN; ++t) {
        int r = rbase + t;
        float are = (float)a2d[(size_t)r * 2048 + d];
        float aim = (float)a2d[(size_t)r * 2048 + 1024 + d];
        float kvv = (float)P[(size_t)r * PLD + 1024 + d]
                  * (float)P[(size_t)r * PLD + 2048 + d];
        float nre = are * hre - aim * him + kvv;
        float nim = are * him + aim * hre;
        hre = nre; him = nim;
        float qv  = (float)P[(size_t)r * PLD + d];
        float yr_ = qv * hre;
        float yi_ = qv * him;
        P[(size_t)r * PLD + d] = (f16)yr_;       // overwrite q with y (safe)
        sre += yr_; sim += yi_; s2 += yr_ * yr_ + yi_ * yi_;
    }
#pragma unroll
    for (int off = 16; off > 0; off >>= 1) {
        sre += __shfl_down(sre, off, 32);
        sim += __shfl_down(sim, off, 32);
        s2  += __shfl_down(s2,  off, 32);
    }
    if ((threadIdx.x & 31) == 0) {
        int idx = (b * 32 + (d >> 5)) * 4;
        atomicAdd(&stats[idx + 0], sre);
        atomicAdd(&stats[idx + 1], sim);
        atomicAdd(&stats[idx + 2], s2);
    }
}

// ------- groupnorm (real) + silu(g)-gate, f16x8, in place on y cols ---------
__global__ __launch_bounds__(256) void gn_gate_k(f16* __restrict__ P,
                                                 const float* __restrict__ stats,
                                                 const float* __restrict__ gn_scale,
                                                 const float* __restrict__ gn_bias) {
    size_t gid = (size_t)blockIdx.x * 256 + threadIdx.x;  // < M*D/8
    int d8  = (int)(gid & 127) * 8;
    int row = (int)(gid >> 7);
    int b   = row >> 12;
    int grp = d8 >> 5;
    const float* st = &stats[(b * 32 + grp) * 4];
    const float invN = 1.0f / 131072.0f;       // S * (D/G)
    float mre = st[0] * invN;
    float mim = st[1] * invN;
    float var = st[2] * invN - mre * mre - mim * mim;
    float rstd = rsqrtf(var + EPSN);
    f16x8 yv = *(f16x8*)&P[(size_t)row * PLD + d8];
    f16x8 gv = *(const f16x8*)&P[(size_t)row * PLD + 3072 + d8];
#pragma unroll
    for (int i = 0; i < 8; ++i) {
        float re = ((float)yv[i] - mre) * rstd * gn_scale[d8 + i] + gn_bias[d8 + i];
        float gx = (float)gv[i];
        yv[i] = (f16)(re * gx * fast_sigmoid(gx));
    }
    *(f16x8*)&P[(size_t)row * PLD + d8] = yv;
}

// ---------------- layernorm over D=1024: out = LN(a + b) --------------------
__device__ __forceinline__ float ldf(const float* p, size_t i) { return p[i]; }
__device__ __forceinline__ float ldf(const f16* p, size_t i)   { return (float)p[i]; }
__device__ __forceinline__ void  stf(float* p, size_t i, float v) { p[i] = v; }
__device__ __forceinline__ void  stf(f16* p, size_t i, float v)   { p[i] = (f16)v; }

__device__ __forceinline__ float block_reduce_sum(float v, float* s4, int tid) {
#pragma unroll
    for (int off = 32; off > 0; off >>= 1) v += __shfl_down(v, off, 64);
    __syncthreads();
    if ((tid & 63) == 0) s4[tid >> 6] = v;
    __syncthreads();
    return s4[0] + s4[1] + s4[2] + s4[3];
}

template <typename TA, typename TB, typename TO>
__global__ __launch_bounds__(256) void ln_k(const TA* __restrict__ a,
                                            const TB* __restrict__ b,
                                            const float* __restrict__ scale,
                                            const float* __restrict__ bias,
                                            TO* __restrict__ out) {
    __shared__ float s4[4];
    int row = blockIdx.x;
    size_t base = (size_t)row * 1024;
    int tid = threadIdx.x;
    float v[4];
    float s = 0.0f;
#pragma unroll
    for (int i = 0; i < 4; ++i) {
        int d = tid + i * 256;
        v[i] = ldf(a, base + d) + ldf(b, base + d);
        s += v[i];
    }
    float mu = block_reduce_sum(s, s4, tid) * (1.0f / 1024.0f);
    float s2 = 0.0f;
#pragma unroll
    for (int i = 0; i < 4; ++i) {
        float dv = v[i] - mu;
        s2 += dv * dv;
    }
    float var = block_reduce_sum(s2, s4, tid) * (1.0f / 1024.0f);
    float rstd = rsqrtf(var + EPSN);
#pragma unroll
    for (int i = 0; i < 4; ++i) {
        int d = tid + i * 256;
        stf(out, base + d, (v[i] - mu) * rstd * scale[d] + bias[d]);
    }
}

// ---------------------------------------------------------------------------
extern "C" void kernel_launch(void* const* d_in, const int* in_sizes, int n_in,
                              void* d_out, int out_size, void* d_ws, size_t ws_size,
                              hipStream_t stream) {
    const float* x        = (const float*)d_in[0];
    const float* Wq       = (const float*)d_in[1];
    const float* Wk       = (const float*)d_in[2];
    const float* Wv       = (const float*)d_in[3];
    const float* Wa       = (const float*)d_in[4];
    const float* Wg       = (const float*)d_in[5];
    const float* Wo       = (const float*)d_in[6];
    const float* gn_scale = (const float*)d_in[7];
    const float* gn_bias  = (const float*)d_in[8];
    const float* ln1_s    = (const float*)d_in[9];
    const float* ln1_b    = (const float*)d_in[10];
    const float* W1       = (const float*)d_in[11];
    const float* b1       = (const float*)d_in[12];
    const float* W2       = (const float*)d_in[13];
    const float* b2       = (const float*)d_in[14];
    const float* ln2_s    = (const float*)d_in[15];
    const float* ln2_b    = (const float*)d_in[16];
    float* out = (float*)d_out;

    char* base = (char*)d_ws;
    f16* W1T = (f16*)(base + 0 * MiB);    // [4096, 1024]
    f16* W2T = (f16*)(base + 8 * MiB);    // [1024, 4096]
    f16* PWT = (f16*)(base + 16 * MiB);   // [4096, 1024] = [Wq|Wk|Wv|Wg]^T
    f16* WoT = (f16*)(base + 24 * MiB);   // [1024, 1024]
    f16* WaT = (f16*)(base + 26 * MiB);   // [2048, 1024]
    float4* chunk = (float4*)(base + 30 * MiB);
    float2* carry = (float2*)(base + 34 * MiB);
    float*  stats = (float*)(base + 36 * MiB);
    f16* xb  = (f16*)(base + 37 * MiB);   // [M,1024] fp16 = 32 MiB
    f16* P   = (f16*)(base + 69 * MiB);   // [M,4096] fp16 = 128 MiB, ends 197
    // aliases (lifetimes verified):
    f16*   ab = (f16*)d_out;              // [M,2048] fp16 = 64 MiB; dead after pass3
    f16*   yo = (f16*)d_out;              // Wo out [M,1024] f16; a dead by then
    f16*   x1 = xb;                       // post-ln1; xb dead after projections
    f16*   h1 = P;                        // [M,F] f16 = 128 MiB; P dead after Wo
    float* h2 = (float*)d_out;            // fp32 [M,D]; yo dead after ln1

    dim3 blk(256);
    dim3 gblk(512);

    // 0. conversions (PWT rows: 0 q | 1024 k | 2048 v | 3072 g)
    f2h_k<<<Mrows, blk, 0, stream>>>(x, xb);
    wtrans_k<<<dim3(128, 32), blk, 0, stream>>>(W1, W1T, Dd, Ff);
    wtrans_k<<<dim3(32, 128), blk, 0, stream>>>(W2, W2T, Ff, Dd);
    wtrans_k<<<dim3(32, 32),  blk, 0, stream>>>(Wq, PWT + 0u * 1048576, Dd, Dd);
    wtrans_k<<<dim3(32, 32),  blk, 0, stream>>>(Wk, PWT + 1u * 1048576, Dd, Dd);
    wtrans_k<<<dim3(32, 32),  blk, 0, stream>>>(Wv, PWT + 2u * 1048576, Dd, Dd);
    wtrans_k<<<dim3(32, 32),  blk, 0, stream>>>(Wg, PWT + 3u * 1048576, Dd, Dd);
    wtrans_k<<<dim3(32, 32),  blk, 0, stream>>>(Wo, WoT, Dd, Dd);
    wtrans_k<<<dim3(64, 32),  blk, 0, stream>>>(Wa, WaT, Dd, 2 * Dd);

    // 1. projections: one N=4096 GEMM (q|k|v|g) + one N=2048 (a)
    mgemm_k<0, f16><<<dim3(16, 64), gblk, 0, stream>>>(xb, Dd, PWT, P, PLD, Mrows, 4096, Dd, nullptr);
    mgemm_k<0, f16><<<dim3(8, 64),  gblk, 0, stream>>>(xb, Dd, WaT, ab, 2048, Mrows, 2048, Dd, nullptr);

    // 2. a transform (fp16, in place in d_out)
    a_transform_k<<<MD / (256 * 8), blk, 0, stream>>>(ab);

    // 3. chunked scan (k*v inline; y in-place over q cols of P)
    scan_pass1_k<<<CBD / 256, blk, 0, stream>>>(ab, P, chunk);
    scan_pass2_k<<<BD / 256, blk, 0, stream>>>(chunk, carry, stats);
    scan_pass3_k<<<CBD / 256, blk, 0, stream>>>(ab, P, carry, stats);

    // 4. groupnorm + silu(g) gate (in place on y cols of P)
    gn_gate_k<<<MD / (256 * 8), blk, 0, stream>>>(P, stats, gn_scale, gn_bias);

    // 5. output projection (A = y cols of P, lda=PLD) + ln1
    mgemm_k<0, f16><<<dim3(4, 64), gblk, 0, stream>>>(P, PLD, WoT, yo, Dd, Mrows, Dd, Dd, nullptr);
    ln_k<float, f16, f16><<<Mrows, blk, 0, stream>>>(x, yo, ln1_s, ln1_b, x1);

    // 6. MLP (h1 overlays P; h2 -> d_out fp32)
    mgemm_k<1, f16  ><<<dim3(16, 64), gblk, 0, stream>>>(x1, Dd, W1T, h1, Ff, Mrows, Ff, Dd, b1);
    mgemm_k<2, float><<<dim3(4, 64),  gblk, 0, stream>>>(h1, Ff, W2T, h2, Dd, Mrows, Dd, Ff, b2);

    // 7. final layernorm -> out (in place over h2: per-thread read-then-write)
    ln_k<f16, float, float><<<Mrows, blk, 0, stream>>>(x1, h2, ln2_s, ln2_b, out);
}

// Round 6
// 893.806 us; speedup vs baseline: 1.5257x; 1.0281x over previous
//
#include <hip/hip_runtime.h>
#include <cstdint>
#include <cstddef>

// ---------------------------------------------------------------------------
// GateLoop block, round 11: m201-style sub-phase GEMM schedule.
//   r10's monolithic phase {read 12 -> vmcnt -> bar -> 32 MFMA -> bar} made
//   the LDS pipe (~1150cy) and matrix pipe (~1240cy) take turns (MfmaUtil
//   30%). m201 proves the same per-wave geometry at 62% with fine phases.
//   r11: BK=64, 2 LDS dbuf (128 KiB), 4 sub-phases per K-tile:
//     P1: read A[0:4]+B[0:2] (12); stage A-halves of t+1; bar; 16 MFMA; bar
//     P2: read B[2:4] (4);     stage B-halves of t+1; bar; 16 MFMA; bar
//     P3: read A[4:8] (8);                            bar; 16 MFMA; bar
//     P4: vmcnt(0) (stages landed ~2 phases ago);     bar; 16 MFMA; bar
//   B frags (8) live whole tile; A frags (8) streamed in halves.
//   New 8-chunk XOR swizzle for 128-B rows (rows x 64 f16): stored chunk =
//   logical ^ (row&7); applied BOTH on pre-swizzled gload source and
//   ds_read offset (both-sides rule). Even 8-lane/chunk spread = LDS
//   minimum = conflict-free.
//   Regs: acc 128 + A 32 + B 32 + addr ~25 < 256 (launch_bounds(512,2)).
//   Carried: 256x256 tile, 8 waves 128x64, XCD swizzle, fast gelu/sigmoid,
//   consolidated projections, vectorized pointwise kernels.
//
// Pipeline:
//   0. x -> fp16; weights -> transposed fp16 [N,K] (qkvg stacked)
//   1. mgemm x@[Wq|Wk|Wv|Wg] -> P[M,4096]; x@Wa -> ab (d_out)
//   2. a_transform in place (fp16, d_out)
//   3. chunked scan (3 passes, fp32 state); k*v inline;
//      pass3 writes y in-place over P's q columns
//   4. gn_gate + silu(g) (vectorized, in place on y cols of P)
//   5. mgemm y@Wo -> yo (d_out); ln1 -> x1 (xb slot)
//   6. mgemm x1@W1(+b1,fast gelu) -> h1 (overlays P); h1@W2(+b2) -> h2 (d_out)
//   7. ln2(x1 + h2) -> out (in place over h2)
//
// ws layout (MiB): 0 W1T(8) | 8 W2T(8) | 16 PWT(8) | 24 WoT(2) | 26 WaT(4) |
//   30 chunk(4) | 34 carry(2) | 36 stats | 37 xb(32) | 69 P(128) | 197 end.
// Aliases: ab & yo & h2 -> d_out; y over P q-cols; h1 -> P; x1 -> xb.
// ---------------------------------------------------------------------------

#define EPSN 1e-6f

typedef _Float16 f16;
typedef _Float16 f16x8 __attribute__((ext_vector_type(8)));
typedef _Float16 f16x4 __attribute__((ext_vector_type(4)));
typedef float    f32x4 __attribute__((ext_vector_type(4)));

static constexpr int    Bb     = 4;
static constexpr int    Ss     = 4096;
static constexpr int    Dd     = 1024;
static constexpr int    Ff     = 4096;
static constexpr int    Mrows  = Bb * Ss;                  // 16384
static constexpr size_t MD     = (size_t)Mrows * Dd;       // 16777216
static constexpr int    CHUNKS = 64;
static constexpr int    CLEN   = Ss / CHUNKS;              // 64
static constexpr int    BD     = Bb * Dd;                  // 4096
static constexpr int    CBD    = CHUNKS * BD;              // 262144
static constexpr size_t MiB    = 1024 * 1024;
static constexpr int    PLD    = 4096;                     // P row stride

__device__ __forceinline__ float fast_sigmoid(float x) {
    float e = __builtin_amdgcn_exp2f(-1.4426950408889634f * x);
    return __builtin_amdgcn_rcpf(1.0f + e);
}
__device__ __forceinline__ float gelu_tanh(float x) {
    float z = 0.7978845608028654f * (x + 0.044715f * x * x * x);
    z = fminf(fmaxf(z, -10.0f), 10.0f);          // tanh(+-10)=+-1 to fp32
    float e = __builtin_amdgcn_exp2f(2.885390081777927f * z);   // e^{2z}
    float t = (e - 1.0f) * __builtin_amdgcn_rcpf(e + 1.0f);
    return 0.5f * x * (1.0f + t);
}

// async global->LDS, 16 B per lane; lds dest = base + lane*16 (wave-uniform base)
__device__ __forceinline__ void async16(const void* g, void* l) {
    __builtin_amdgcn_global_load_lds(
        (const __attribute__((address_space(1))) unsigned int*)(uintptr_t)g,
        (__attribute__((address_space(3))) unsigned int*)(uintptr_t)l,
        16, 0, 0);
}

// ------- MFMA GEMM: C[M,N](ldc) = A[M,K](lda,f16) @ Bt[N,K](f16)^T ----------
// Tile 256x256, BK=64, 8 waves of 128x64 (acc 8x4), 2 LDS dbuf, 4 sub-phases.
// EPI: 0 none | 1 bias+gelu | 2 bias
template <int EPI, typename TC>
__global__ __launch_bounds__(512, 2) void mgemm_k(const f16* __restrict__ A, int lda,
                                                  const f16* __restrict__ Bt,
                                                  TC* __restrict__ C, int ldc,
                                                  int M, int N, int K,
                                                  const float* __restrict__ bias) {
    __shared__ f16 sA[2 * 256 * 64];   // 32 KiB / buffer
    __shared__ f16 sB[2 * 256 * 64];   // 32 KiB / buffer -> 128 KiB total
    const int tid  = threadIdx.x;
    const int wave = tid >> 6;        // 0..7
    const int lane = tid & 63;

    // XCD-chunked bijective swizzle (all grids have nwg % 8 == 0)
    const int gx  = gridDim.x;
    const int nwg = gx * gridDim.y;
    int bid = blockIdx.y * gx + blockIdx.x;
    bid = (bid & 7) * (nwg >> 3) + (bid >> 3);
    const int bm = (bid / gx) * 256;
    const int bn = (bid % gx) * 256;

    const int rw = (wave >> 2) * 128; // wave row offset (0 or 128)
    const int cw = (wave & 3) * 64;   // wave col offset (0..192)

    // staging: per gload 64 lanes x 16B = 8 rows x 128B. lane l -> row
    // srow + (l>>3), stored chunk (l&7). Pre-swizzled global chunk =
    // (l&7) ^ (row&7) = (l&7) ^ (l>>3)   (row&7 == l>>3 here).
    const int swz  = (((lane & 7) ^ (lane >> 3)) & 7) * 8;
    const int srow = wave * 16 + (lane >> 3);
    const f16* gA0 = A  + (size_t)(bm + srow) * lda + swz;
    const f16* gB0 = Bt + (size_t)(bn + srow) * K   + swz;

    f32x4 acc[8][4] = {};

    // fragment read: logical chunk c = kk*4 + (lane>>4); stored at
    // c ^ (row&7), row&7 = fr&7 = lane&7. off0 = ((lane>>4)^(lane&7))*8,
    // kk=1 flips chunk bit2 -> ^32 f16.
    const int fr   = lane & 15;
    const int off0 = (((lane >> 4) ^ lane) & 7) * 8;

    const int NT = K >> 6;            // K-tiles of 64 (K 1024/4096)

// stage one 8-row slab: half h (0/1 = rows 0-127/128-255), gload g (0/1)
#define STG(dst, gp, ld, kOff, h, g)                                           \
    async16((gp) + (size_t)((h) * 128 + (g) * 8) * (ld) + (kOff),              \
            (dst) + ((h) * 128 + wave * 16 + (g) * 8) * 64)

#define LDA4(ib, buf)                                                          \
    _Pragma("unroll") for (int i = 0; i < 4; ++i) {                            \
        const int row_ = (rw + ((ib) + i) * 16 + fr) * 64;                     \
        a_[i][0] = *(const f16x8*)&(buf)[row_ + off0];                         \
        a_[i][1] = *(const f16x8*)&(buf)[row_ + (off0 ^ 32)];                  \
    }
#define LDB2(arr, jb, buf)                                                     \
    _Pragma("unroll") for (int j = 0; j < 2; ++j) {                            \
        const int row_ = (cw + ((jb) + j) * 16 + fr) * 64;                     \
        arr[j][0] = *(const f16x8*)&(buf)[row_ + off0];                        \
        arr[j][1] = *(const f16x8*)&(buf)[row_ + (off0 ^ 32)];                 \
    }
#define MMQ(iq, jq, barr)                                                      \
    __builtin_amdgcn_s_setprio(1);                                             \
    _Pragma("unroll") for (int i = 0; i < 4; ++i)                              \
        _Pragma("unroll") for (int j = 0; j < 2; ++j)                          \
            _Pragma("unroll") for (int kk = 0; kk < 2; ++kk)                   \
                acc[(iq) + i][(jq) + j] = __builtin_amdgcn_mfma_f32_16x16x32_f16( \
                    a_[i][kk], barr[j][kk], acc[(iq) + i][(jq) + j], 0, 0, 0); \
    __builtin_amdgcn_s_setprio(0);

    // prologue: stage tile 0 fully into buffer 0; drain; publish
    STG(sA, gA0, lda, 0, 0, 0); STG(sA, gA0, lda, 0, 0, 1);
    STG(sA, gA0, lda, 0, 1, 0); STG(sA, gA0, lda, 0, 1, 1);
    STG(sB, gB0, K,   0, 0, 0); STG(sB, gB0, K,   0, 0, 1);
    STG(sB, gB0, K,   0, 1, 0); STG(sB, gB0, K,   0, 1, 1);
    asm volatile("s_waitcnt vmcnt(0)" ::: "memory");
    __builtin_amdgcn_s_barrier();

    for (int t = 0; t < NT; ++t) {
        const f16* rdA = sA + (t & 1) * 16384;
        const f16* rdB = sB + (t & 1) * 16384;
        f16* stA = sA + ((t + 1) & 1) * 16384;
        f16* stB = sB + ((t + 1) & 1) * 16384;
        const int kS = (t + 1) * 64;
        const bool doSt = (t + 1) < NT;
        f16x8 a_[4][2], bA[2][2], bB[2][2];

        // P1: A[0:4], B[0:2]; stage A halves of t+1
        LDA4(0, rdA)
        LDB2(bA, 0, rdB)
        if (doSt) {
            STG(stA, gA0, lda, kS, 0, 0); STG(stA, gA0, lda, kS, 0, 1);
            STG(stA, gA0, lda, kS, 1, 0); STG(stA, gA0, lda, kS, 1, 1);
        }
        __builtin_amdgcn_s_barrier();
        MMQ(0, 0, bA)
        __builtin_amdgcn_s_barrier();

        // P2: B[2:4]; stage B halves of t+1
        LDB2(bB, 2, rdB)
        if (doSt) {
            STG(stB, gB0, K, kS, 0, 0); STG(stB, gB0, K, kS, 0, 1);
            STG(stB, gB0, K, kS, 1, 0); STG(stB, gB0, K, kS, 1, 1);
        }
        __builtin_amdgcn_s_barrier();
        MMQ(0, 2, bB)
        __builtin_amdgcn_s_barrier();

        // P3: A[4:8]
        LDA4(4, rdA)
        __builtin_amdgcn_s_barrier();
        MMQ(4, 2, bB)
        __builtin_amdgcn_s_barrier();

        // P4: drain this tile's stages (issued P1/P2, ~2 phases of cover)
        asm volatile("s_waitcnt vmcnt(0)" ::: "memory");
        __builtin_amdgcn_s_barrier();
        MMQ(4, 0, bA)
        __builtin_amdgcn_s_barrier();
    }
#undef STG
#undef LDA4
#undef LDB2
#undef MMQ

    // epilogue: C row = (lane>>4)*4 + reg, col = lane&15  (dtype-independent)
    const int er = (lane >> 4) * 4;
    const int ec = lane & 15;
#pragma unroll
    for (int i = 0; i < 8; ++i) {
#pragma unroll
        for (int j = 0; j < 4; ++j) {
            const int col = bn + cw + j * 16 + ec;
#pragma unroll
            for (int r = 0; r < 4; ++r) {
                const size_t row = (size_t)(bm + rw + i * 16 + er + r);
                float o = acc[i][j][r];
                if (EPI == 1 || EPI == 2) o += bias[col];
                if (EPI == 1) o = gelu_tanh(o);
                if (sizeof(TC) == 4) ((float*)C)[row * ldc + col] = o;
                else                 ((f16*)C)[row * ldc + col] = (f16)o;
            }
        }
    }
}

// ---------------- weight transpose+convert: Wt[n][k] = f16(W[k][n]) ---------
__global__ __launch_bounds__(256) void wtrans_k(const float* __restrict__ W,
                                                f16* __restrict__ Wt,
                                                int K, int N) {
    __shared__ float t[32][33];
    const int n0 = blockIdx.x * 32, k0 = blockIdx.y * 32;
    const int tx = threadIdx.x & 31, ty = threadIdx.x >> 5;   // 8 rows
#pragma unroll
    for (int i = 0; i < 32; i += 8)
        t[ty + i][tx] = W[(size_t)(k0 + ty + i) * N + n0 + tx];
    __syncthreads();
#pragma unroll
    for (int i = 0; i < 32; i += 8)
        Wt[(size_t)(n0 + ty + i) * K + k0 + tx] = (f16)t[tx][ty + i];
}

// ---------------- x fp32 -> fp16 --------------------------------------------
__global__ __launch_bounds__(256) void f2h_k(const float* __restrict__ x,
                                             f16* __restrict__ xh) {
    size_t i = ((size_t)blockIdx.x * 256 + threadIdx.x) * 4;
    float4 v = *(const float4*)&x[i];
    f16x4 s;
    s.x = (f16)v.x; s.y = (f16)v.y; s.z = (f16)v.z; s.w = (f16)v.w;
    *(f16x4*)&xh[i] = s;
}

// ------- a transform: a_c = sigmoid(|a|)*a/|a| (fp16 in place, x8) ----------
__global__ __launch_bounds__(256) void a_transform_k(f16* __restrict__ a2d) {
    size_t gid = (size_t)blockIdx.x * 256 + threadIdx.x;   // < M*D/8
    int    j8  = (int)(gid & 127) * 8;
    size_t row = gid >> 7;
    f16x8 vr = *(f16x8*)&a2d[row * 2048 + j8];
    f16x8 vi = *(f16x8*)&a2d[row * 2048 + 1024 + j8];
#pragma unroll
    for (int i = 0; i < 8; ++i) {
        float ar = (float)vr[i], ai = (float)vi[i];
        float mag = sqrtf(ar * ar + ai * ai);
        float sg  = fast_sigmoid(mag);
        float re, im;
        if (mag > 1e-30f) { float s = sg * __builtin_amdgcn_rcpf(mag); re = ar * s; im = ai * s; }
        else              { re = sg; im = 0.0f; }
        vr[i] = (f16)re; vi[i] = (f16)im;
    }
    *(f16x8*)&a2d[row * 2048 + j8]        = vr;
    *(f16x8*)&a2d[row * 2048 + 1024 + j8] = vi;
}

// ---------------- chunked complex scan (fp32 state) -------------------------
// P columns: q 0..1023 | k 1024..2047 | v 2048..3071 | g 3072..4095
__global__ __launch_bounds__(256) void scan_pass1_k(const f16* __restrict__ a2d,
                                                    const f16* __restrict__ P,
                                                    float4* __restrict__ chunk) {
    int tid = blockIdx.x * 256 + threadIdx.x;    // < CBD
    int d   = tid & 1023;
    int t1  = tid >> 10;
    int b   = t1 & 3;
    int c   = t1 >> 2;
    int t0  = c * CLEN;
    int rbase = b * Ss;
    float Are = 1.0f, Aim = 0.0f, Hre = 0.0f, Him = 0.0f;
    for (int t = t0; t < t0 + CLEN; ++t) {
        int r = rbase + t;
        float are = (float)a2d[(size_t)r * 2048 + d];
        float aim = (float)a2d[(size_t)r * 2048 + 1024 + d];
        float kvv = (float)P[(size_t)r * PLD + 1024 + d]
                  * (float)P[(size_t)r * PLD + 2048 + d];
        float hre = are * Hre - aim * Him + kvv;
        float him = are * Him + aim * Hre;
        Hre = hre; Him = him;
        float pre = are * Are - aim * Aim;
        float pim = are * Aim + aim * Are;
        Are = pre; Aim = pim;
    }
    chunk[tid] = make_float4(Are, Aim, Hre, Him);
}

__global__ __launch_bounds__(256) void scan_pass2_k(const float4* __restrict__ chunk,
                                                    float2* __restrict__ carry,
                                                    float* __restrict__ stats) {
    int tid = blockIdx.x * blockDim.x + threadIdx.x;  // < B*D = 4096
    if (tid < 512) stats[tid] = 0.0f;                 // ws is poisoned: zero gn stats
    float hre = 0.0f, him = 0.0f;
    for (int c = 0; c < CHUNKS; ++c) {
        int task = c * BD + tid;
        float4 ch = chunk[task];
        carry[task] = make_float2(hre, him);
        float nre = ch.x * hre - ch.y * him + ch.z;
        float nim = ch.x * him + ch.y * hre + ch.w;
        hre = nre; him = nim;
    }
}

// pass3: y written in place over P's q columns (per-elem read-then-write)
__global__ __launch_bounds__(256) void scan_pass3_k(const f16* __restrict__ a2d,
                                                    f16* __restrict__ P,
                                                    const float2* __restrict__ carry,
                                                    float* __restrict__ stats) {
    int tid = blockIdx.x * 256 + threadIdx.x;    // < CBD
    int d   = tid & 1023;
    int t1  = tid >> 10;
    int b   = t1 & 3;
    int c   = t1 >> 2;
    int t0  = c * CLEN;
    int rbase = b * Ss;
    float2 cr = carry[tid];
    float hre = cr.x, him = cr.y;
    float sre = 0.0f, sim = 0.0f, s2 = 0.0f;
    for (int t = t0; t < t0 + CLEN; ++t) {
        int r = rbase + t;
        float are = (float)a2d[(size_t)r * 2048 + d];
        float aim = (float)a2d[(size_t)r * 2048 + 1024 + d];
        float kvv = (float)P[(size_t)r * PLD + 1024 + d]
                  * (float)P[(size_t)r * PLD + 2048 + d];
        float nre = are * hre - aim * him + kvv;
        float nim = are * him + aim * hre;
        hre = nre; him = nim;
        float qv  = (float)P[(size_t)r * PLD + d];
        float yr_ = qv * hre;
        float yi_ = qv * him;
        P[(size_t)r * PLD + d] = (f16)yr_;       // overwrite q with y (safe)
        sre += yr_; sim += yi_; s2 += yr_ * yr_ + yi_ * yi_;
    }
#pragma unroll
    for (int off = 16; off > 0; off >>= 1) {
        sre += __shfl_down(sre, off, 32);
        sim += __shfl_down(sim, off, 32);
        s2  += __shfl_down(s2,  off, 32);
    }
    if ((threadIdx.x & 31) == 0) {
        int idx = (b * 32 + (d >> 5)) * 4;
        atomicAdd(&stats[idx + 0], sre);
        atomicAdd(&stats[idx + 1], sim);
        atomicAdd(&stats[idx + 2], s2);
    }
}

// ------- groupnorm (real) + silu(g)-gate, f16x8, in place on y cols ---------
__global__ __launch_bounds__(256) void gn_gate_k(f16* __restrict__ P,
                                                 const float* __restrict__ stats,
                                                 const float* __restrict__ gn_scale,
                                                 const float* __restrict__ gn_bias) {
    size_t gid = (size_t)blockIdx.x * 256 + threadIdx.x;  // < M*D/8
    int d8  = (int)(gid & 127) * 8;
    int row = (int)(gid >> 7);
    int b   = row >> 12;
    int grp = d8 >> 5;
    const float* st = &stats[(b * 32 + grp) * 4];
    const float invN = 1.0f / 131072.0f;       // S * (D/G)
    float mre = st[0] * invN;
    float mim = st[1] * invN;
    float var = st[2] * invN - mre * mre - mim * mim;
    float rstd = rsqrtf(var + EPSN);
    f16x8 yv = *(f16x8*)&P[(size_t)row * PLD + d8];
    f16x8 gv = *(const f16x8*)&P[(size_t)row * PLD + 3072 + d8];
#pragma unroll
    for (int i = 0; i < 8; ++i) {
        float re = ((float)yv[i] - mre) * rstd * gn_scale[d8 + i] + gn_bias[d8 + i];
        float gx = (float)gv[i];
        yv[i] = (f16)(re * gx * fast_sigmoid(gx));
    }
    *(f16x8*)&P[(size_t)row * PLD + d8] = yv;
}

// ---------------- layernorm over D=1024: out = LN(a + b) --------------------
__device__ __forceinline__ float ldf(const float* p, size_t i) { return p[i]; }
__device__ __forceinline__ float ldf(const f16* p, size_t i)   { return (float)p[i]; }
__device__ __forceinline__ void  stf(float* p, size_t i, float v) { p[i] = v; }
__device__ __forceinline__ void  stf(f16* p, size_t i, float v)   { p[i] = (f16)v; }

__device__ __forceinline__ float block_reduce_sum(float v, float* s4, int tid) {
#pragma unroll
    for (int off = 32; off > 0; off >>= 1) v += __shfl_down(v, off, 64);
    __syncthreads();
    if ((tid & 63) == 0) s4[tid >> 6] = v;
    __syncthreads();
    return s4[0] + s4[1] + s4[2] + s4[3];
}

template <typename TA, typename TB, typename TO>
__global__ __launch_bounds__(256) void ln_k(const TA* __restrict__ a,
                                            const TB* __restrict__ b,
                                            const float* __restrict__ scale,
                                            const float* __restrict__ bias,
                                            TO* __restrict__ out) {
    __shared__ float s4[4];
    int row = blockIdx.x;
    size_t base = (size_t)row * 1024;
    int tid = threadIdx.x;
    float v[4];
    float s = 0.0f;
#pragma unroll
    for (int i = 0; i < 4; ++i) {
        int d = tid + i * 256;
        v[i] = ldf(a, base + d) + ldf(b, base + d);
        s += v[i];
    }
    float mu = block_reduce_sum(s, s4, tid) * (1.0f / 1024.0f);
    float s2 = 0.0f;
#pragma unroll
    for (int i = 0; i < 4; ++i) {
        float dv = v[i] - mu;
        s2 += dv * dv;
    }
    float var = block_reduce_sum(s2, s4, tid) * (1.0f / 1024.0f);
    float rstd = rsqrtf(var + EPSN);
#pragma unroll
    for (int i = 0; i < 4; ++i) {
        int d = tid + i * 256;
        stf(out, base + d, (v[i] - mu) * rstd * scale[d] + bias[d]);
    }
}

// ---------------------------------------------------------------------------
extern "C" void kernel_launch(void* const* d_in, const int* in_sizes, int n_in,
                              void* d_out, int out_size, void* d_ws, size_t ws_size,
                              hipStream_t stream) {
    const float* x        = (const float*)d_in[0];
    const float* Wq       = (const float*)d_in[1];
    const float* Wk       = (const float*)d_in[2];
    const float* Wv       = (const float*)d_in[3];
    const float* Wa       = (const float*)d_in[4];
    const float* Wg       = (const float*)d_in[5];
    const float* Wo       = (const float*)d_in[6];
    const float* gn_scale = (const float*)d_in[7];
    const float* gn_bias  = (const float*)d_in[8];
    const float* ln1_s    = (const float*)d_in[9];
    const float* ln1_b    = (const float*)d_in[10];
    const float* W1       = (const float*)d_in[11];
    const float* b1       = (const float*)d_in[12];
    const float* W2       = (const float*)d_in[13];
    const float* b2       = (const float*)d_in[14];
    const float* ln2_s    = (const float*)d_in[15];
    const float* ln2_b    = (const float*)d_in[16];
    float* out = (float*)d_out;

    char* base = (char*)d_ws;
    f16* W1T = (f16*)(base + 0 * MiB);    // [4096, 1024]
    f16* W2T = (f16*)(base + 8 * MiB);    // [1024, 4096]
    f16* PWT = (f16*)(base + 16 * MiB);   // [4096, 1024] = [Wq|Wk|Wv|Wg]^T
    f16* WoT = (f16*)(base + 24 * MiB);   // [1024, 1024]
    f16* WaT = (f16*)(base + 26 * MiB);   // [2048, 1024]
    float4* chunk = (float4*)(base + 30 * MiB);
    float2* carry = (float2*)(base + 34 * MiB);
    float*  stats = (float*)(base + 36 * MiB);
    f16* xb  = (f16*)(base + 37 * MiB);   // [M,1024] fp16 = 32 MiB
    f16* P   = (f16*)(base + 69 * MiB);   // [M,4096] fp16 = 128 MiB, ends 197
    // aliases (lifetimes verified):
    f16*   ab = (f16*)d_out;              // [M,2048] fp16 = 64 MiB; dead after pass3
    f16*   yo = (f16*)d_out;              // Wo out [M,1024] f16; a dead by then
    f16*   x1 = xb;                       // post-ln1; xb dead after projections
    f16*   h1 = P;                        // [M,F] f16 = 128 MiB; P dead after Wo
    float* h2 = (float*)d_out;            // fp32 [M,D]; yo dead after ln1

    dim3 blk(256);
    dim3 gblk(512);

    // 0. conversions (PWT rows: 0 q | 1024 k | 2048 v | 3072 g)
    f2h_k<<<Mrows, blk, 0, stream>>>(x, xb);
    wtrans_k<<<dim3(128, 32), blk, 0, stream>>>(W1, W1T, Dd, Ff);
    wtrans_k<<<dim3(32, 128), blk, 0, stream>>>(W2, W2T, Ff, Dd);
    wtrans_k<<<dim3(32, 32),  blk, 0, stream>>>(Wq, PWT + 0u * 1048576, Dd, Dd);
    wtrans_k<<<dim3(32, 32),  blk, 0, stream>>>(Wk, PWT + 1u * 1048576, Dd, Dd);
    wtrans_k<<<dim3(32, 32),  blk, 0, stream>>>(Wv, PWT + 2u * 1048576, Dd, Dd);
    wtrans_k<<<dim3(32, 32),  blk, 0, stream>>>(Wg, PWT + 3u * 1048576, Dd, Dd);
    wtrans_k<<<dim3(32, 32),  blk, 0, stream>>>(Wo, WoT, Dd, Dd);
    wtrans_k<<<dim3(64, 32),  blk, 0, stream>>>(Wa, WaT, Dd, 2 * Dd);

    // 1. projections: one N=4096 GEMM (q|k|v|g) + one N=2048 (a)
    mgemm_k<0, f16><<<dim3(16, 64), gblk, 0, stream>>>(xb, Dd, PWT, P, PLD, Mrows, 4096, Dd, nullptr);
    mgemm_k<0, f16><<<dim3(8, 64),  gblk, 0, stream>>>(xb, Dd, WaT, ab, 2048, Mrows, 2048, Dd, nullptr);

    // 2. a transform (fp16, in place in d_out)
    a_transform_k<<<MD / (256 * 8), blk, 0, stream>>>(ab);

    // 3. chunked scan (k*v inline; y in-place over q cols of P)
    scan_pass1_k<<<CBD / 256, blk, 0, stream>>>(ab, P, chunk);
    scan_pass2_k<<<BD / 256, blk, 0, stream>>>(chunk, carry, stats);
    scan_pass3_k<<<CBD / 256, blk, 0, stream>>>(ab, P, carry, stats);

    // 4. groupnorm + silu(g) gate (in place on y cols of P)
    gn_gate_k<<<MD / (256 * 8), blk, 0, stream>>>(P, stats, gn_scale, gn_bias);

    // 5. output projection (A = y cols of P, lda=PLD) + ln1
    mgemm_k<0, f16><<<dim3(4, 64), gblk, 0, stream>>>(P, PLD, WoT, yo, Dd, Mrows, Dd, Dd, nullptr);
    ln_k<float, f16, f16><<<Mrows, blk, 0, stream>>>(x, yo, ln1_s, ln1_b, x1);

    // 6. MLP (h1 overlays P; h2 -> d_out fp32)
    mgemm_k<1, f16  ><<<dim3(16, 64), gblk, 0, stream>>>(x1, Dd, W1T, h1, Ff, Mrows, Ff, Dd, b1);
    mgemm_k<2, float><<<dim3(4, 64),  gblk, 0, stream>>>(h1, Ff, W2T, h2, Dd, Mrows, Dd, Ff, b2);

    // 7. final layernorm -> out (in place over h2: per-thread read-then-write)
    ln_k<f16, float, float><<<Mrows, blk, 0, stream>>>(x1, h2, ln2_s, ln2_b, out);
}

// Round 7
// 892.114 us; speedup vs baseline: 1.5286x; 1.0019x over previous
//
#include <hip/hip_runtime.h>
#include <cstdint>
#include <cstddef>

// ---------------------------------------------------------------------------
// GateLoop block, round 12: m201-aligned balanced phases + counted vmcnt.
//   r11 (36% MfmaUtil) had read-lumpy phases (12/4/8/0 ds_read/wave) and a
//   vmcnt(0) drain every tile: each phase serialized as [block read-burst]
//   then [MFMA]. r12 rebalances to m201's 8/4/8/4 via a k-half-split LDS
//   layout [kk][256][32] per matrix per buffer (same bytes):
//     P1: read A[0:4]k0 + B[0:4]k0 (8); stage A-k0(t+1);            16 MFMA
//     P2: read A[4:8]k0 (4);           stage B-k0(t+1); vmcnt(4);   16 MFMA
//     P3: read A[0:4]k1 + B[0:4]k1 (8); stage A-k1(t+1);            16 MFMA
//     P4: read A[4:8]k1 (4);           stage B-k1(t+1); vmcnt(4);   16 MFMA
//   vmcnt(4) leaves exactly this tile's 4 newest stage-loads in flight and
//   drains the older half-tiles needed by the next reads (chronological
//   order proof in-line). Never 0 mid-loop; single vmcnt(0) at last tile P2.
//   Swizzle (both-sides, re-derived for [kk][256][32], 64-B half-rows):
//     stage global pre-swizzle ((l&3)^((l>>3)&3))*8 ; frag read offset
//     (((l>>4)^(l>>1))&3)*8  -> <=2-way bank aliasing (free).
//   Regs: acc 128 + a_ 16 + b_ 16 + addr ~25 < 256 (launch_bounds(512,2)).
//   Carried: 256x256 tile, 8 waves 128x64, XCD swizzle, fast gelu/sigmoid,
//   consolidated projections, vectorized pointwise kernels.
//
// Pipeline:
//   0. x -> fp16; weights -> transposed fp16 [N,K] (qkvg stacked)
//   1. mgemm x@[Wq|Wk|Wv|Wg] -> P[M,4096]; x@Wa -> ab (d_out)
//   2. a_transform in place (fp16, d_out)
//   3. chunked scan (3 passes, fp32 state); k*v inline;
//      pass3 writes y in-place over P's q columns
//   4. gn_gate + silu(g) (vectorized, in place on y cols of P)
//   5. mgemm y@Wo -> yo (d_out); ln1 -> x1 (xb slot)
//   6. mgemm x1@W1(+b1,fast gelu) -> h1 (overlays P); h1@W2(+b2) -> h2 (d_out)
//   7. ln2(x1 + h2) -> out (in place over h2)
//
// ws layout (MiB): 0 W1T(8) | 8 W2T(8) | 16 PWT(8) | 24 WoT(2) | 26 WaT(4) |
//   30 chunk(4) | 34 carry(2) | 36 stats | 37 xb(32) | 69 P(128) | 197 end.
// Aliases: ab & yo & h2 -> d_out; y over P q-cols; h1 -> P; x1 -> xb.
// ---------------------------------------------------------------------------

#define EPSN 1e-6f

typedef _Float16 f16;
typedef _Float16 f16x8 __attribute__((ext_vector_type(8)));
typedef _Float16 f16x4 __attribute__((ext_vector_type(4)));
typedef float    f32x4 __attribute__((ext_vector_type(4)));

static constexpr int    Bb     = 4;
static constexpr int    Ss     = 4096;
static constexpr int    Dd     = 1024;
static constexpr int    Ff     = 4096;
static constexpr int    Mrows  = Bb * Ss;                  // 16384
static constexpr size_t MD     = (size_t)Mrows * Dd;       // 16777216
static constexpr int    CHUNKS = 64;
static constexpr int    CLEN   = Ss / CHUNKS;              // 64
static constexpr int    BD     = Bb * Dd;                  // 4096
static constexpr int    CBD    = CHUNKS * BD;              // 262144
static constexpr size_t MiB    = 1024 * 1024;
static constexpr int    PLD    = 4096;                     // P row stride

__device__ __forceinline__ float fast_sigmoid(float x) {
    float e = __builtin_amdgcn_exp2f(-1.4426950408889634f * x);
    return __builtin_amdgcn_rcpf(1.0f + e);
}
__device__ __forceinline__ float gelu_tanh(float x) {
    float z = 0.7978845608028654f * (x + 0.044715f * x * x * x);
    z = fminf(fmaxf(z, -10.0f), 10.0f);          // tanh(+-10)=+-1 to fp32
    float e = __builtin_amdgcn_exp2f(2.885390081777927f * z);   // e^{2z}
    float t = (e - 1.0f) * __builtin_amdgcn_rcpf(e + 1.0f);
    return 0.5f * x * (1.0f + t);
}

// async global->LDS, 16 B per lane; lds dest = base + lane*16 (wave-uniform base)
__device__ __forceinline__ void async16(const void* g, void* l) {
    __builtin_amdgcn_global_load_lds(
        (const __attribute__((address_space(1))) unsigned int*)(uintptr_t)g,
        (__attribute__((address_space(3))) unsigned int*)(uintptr_t)l,
        16, 0, 0);
}

// ------- MFMA GEMM: C[M,N](ldc) = A[M,K](lda,f16) @ Bt[N,K](f16)^T ----------
// Tile 256x256, BK=64, 8 waves of 128x64 (acc 8x4), 2 LDS dbuf,
// 4 balanced phases/tile, counted vmcnt. EPI: 0 none | 1 bias+gelu | 2 bias
template <int EPI, typename TC>
__global__ __launch_bounds__(512, 2) void mgemm_k(const f16* __restrict__ A, int lda,
                                                  const f16* __restrict__ Bt,
                                                  TC* __restrict__ C, int ldc,
                                                  int M, int N, int K,
                                                  const float* __restrict__ bias) {
    // per buffer per matrix: [kk][256 rows][32 f16]  (32 KiB); 2 buffers
    __shared__ f16 sA[2 * 16384];
    __shared__ f16 sB[2 * 16384];
    const int tid  = threadIdx.x;
    const int wave = tid >> 6;        // 0..7
    const int lane = tid & 63;

    // XCD-chunked bijective swizzle (all grids have nwg % 8 == 0)
    const int gx  = gridDim.x;
    const int nwg = gx * gridDim.y;
    int bid = blockIdx.y * gx + blockIdx.x;
    bid = (bid & 7) * (nwg >> 3) + (bid >> 3);
    const int bm = (bid / gx) * 256;
    const int bn = (bid % gx) * 256;

    const int rw = (wave >> 2) * 128; // wave row offset (0 or 128)
    const int cw = (wave & 3) * 64;   // wave col offset (0..192)

    // staging: one gload = wave's 16 half-rows x 64 B of one k-half.
    // lane l -> row (l>>2), phys chunk (l&3); pre-swizzled global chunk
    // c_log = (l&3) ^ ((row>>1)&3) = (l&3) ^ ((l>>3)&3).
    const int swzcF = (((lane & 3) ^ (lane >> 3)) & 3) * 8;   // f16 units
    const f16* gA0 = A  + (size_t)(bm + wave * 16 + (lane >> 2)) * lda + swzcF;
    const f16* gB0 = Bt + (size_t)(bn + wave * 16 + (lane >> 2)) * K   + swzcF;

    f32x4 acc[8][4] = {};

    // fragment read: phys chunk = fk ^ ((fr>>1)&3); fr=lane&15, fk=lane>>4
    const int fr   = lane & 15;
    const int off0 = (((lane >> 4) ^ (lane >> 1)) & 3) * 8;   // f16 units

    const int NT = K >> 6;            // K-tiles of 64 (K 1024/4096)

// stage gload G (0/1 = rows 0-127/128-255) of k-half KK into buffer SB
#define STGA(SB, KOFF, KK, G)                                                  \
    async16(gA0 + (size_t)(G) * 128 * lda + (KOFF) + (KK) * 32,                \
            sA + (SB) * 16384 + (KK) * 8192 + ((G) * 128 + wave * 16) * 32)
#define STGB(SB, KOFF, KK, G)                                                  \
    async16(gB0 + (size_t)(G) * 128 * K + (KOFF) + (KK) * 32,                  \
            sB + (SB) * 16384 + (KK) * 8192 + ((G) * 128 + wave * 16) * 32)

#define LDA4(IH, KK, BUF)                                                      \
    _Pragma("unroll") for (int i = 0; i < 4; ++i)                              \
        a_[i] = *(const f16x8*)&sA[(BUF) * 16384 + (KK) * 8192 +               \
                                   (rw + ((IH) + i) * 16 + fr) * 32 + off0];
#define LDB4(KK, BUF)                                                          \
    _Pragma("unroll") for (int j = 0; j < 4; ++j)                              \
        b_[j] = *(const f16x8*)&sB[(BUF) * 16384 + (KK) * 8192 +               \
                                   (cw + j * 16 + fr) * 32 + off0];
#define MMQ(IH)                                                                \
    __builtin_amdgcn_s_setprio(1);                                             \
    _Pragma("unroll") for (int i = 0; i < 4; ++i)                              \
        _Pragma("unroll") for (int j = 0; j < 4; ++j)                          \
            acc[(IH) + i][j] = __builtin_amdgcn_mfma_f32_16x16x32_f16(         \
                a_[i], b_[j], acc[(IH) + i][j], 0, 0, 0);                      \
    __builtin_amdgcn_s_setprio(0);

    // prologue: stage tile 0 fully into buffer 0; drain; publish
    STGA(0, 0, 0, 0); STGA(0, 0, 0, 1); STGA(0, 0, 1, 0); STGA(0, 0, 1, 1);
    STGB(0, 0, 0, 0); STGB(0, 0, 0, 1); STGB(0, 0, 1, 0); STGB(0, 0, 1, 1);
    asm volatile("s_waitcnt vmcnt(0)" ::: "memory");
    __builtin_amdgcn_s_barrier();

    for (int t = 0; t < NT; ++t) {
        const int rd = t & 1, st = rd ^ 1;
        const int kS = (t + 1) * 64;
        const bool doSt = (t + 1) < NT;
        f16x8 a_[4], b_[4];

        // P1: A[0:4]k0 + B[0:4]k0 (8 reads); stage A-k0(t+1)
        LDB4(0, rd)
        LDA4(0, 0, rd)
        if (doSt) { STGA(st, kS, 0, 0); STGA(st, kS, 0, 1); }
        __builtin_amdgcn_s_barrier();
        MMQ(0)
        __builtin_amdgcn_s_barrier();

        // P2: A[4:8]k0 (4 reads); stage B-k0(t+1); counted wait
        // (drains A-k1(t)/B-k1(t) staged at t-1.P3/P4 -- needed by P3;
        //  leaves this tile's 4 newest in flight)
        LDA4(4, 0, rd)
        if (doSt) {
            STGB(st, kS, 0, 0); STGB(st, kS, 0, 1);
            asm volatile("s_waitcnt vmcnt(4)" ::: "memory");
        } else {
            asm volatile("s_waitcnt vmcnt(0)" ::: "memory");   // tail only
        }
        __builtin_amdgcn_s_barrier();
        MMQ(4)
        __builtin_amdgcn_s_barrier();

        // P3: A[0:4]k1 + B[0:4]k1 (8 reads); stage A-k1(t+1)
        LDB4(1, rd)
        LDA4(0, 1, rd)
        if (doSt) { STGA(st, kS, 1, 0); STGA(st, kS, 1, 1); }
        __builtin_amdgcn_s_barrier();
        MMQ(0)
        __builtin_amdgcn_s_barrier();

        // P4: A[4:8]k1 (4 reads); stage B-k1(t+1); counted wait
        // (drains A-k0(t+1)/B-k0(t+1) -- needed by t+1.P1)
        LDA4(4, 1, rd)
        if (doSt) {
            STGB(st, kS, 1, 0); STGB(st, kS, 1, 1);
            asm volatile("s_waitcnt vmcnt(4)" ::: "memory");
        }
        __builtin_amdgcn_s_barrier();
        MMQ(4)
        __builtin_amdgcn_s_barrier();
    }
#undef STGA
#undef STGB
#undef LDA4
#undef LDB4
#undef MMQ

    // epilogue: C row = (lane>>4)*4 + reg, col = lane&15  (dtype-independent)
    const int er = (lane >> 4) * 4;
    const int ec = lane & 15;
#pragma unroll
    for (int i = 0; i < 8; ++i) {
#pragma unroll
        for (int j = 0; j < 4; ++j) {
            const int col = bn + cw + j * 16 + ec;
#pragma unroll
            for (int r = 0; r < 4; ++r) {
                const size_t row = (size_t)(bm + rw + i * 16 + er + r);
                float o = acc[i][j][r];
                if (EPI == 1 || EPI == 2) o += bias[col];
                if (EPI == 1) o = gelu_tanh(o);
                if (sizeof(TC) == 4) ((float*)C)[row * ldc + col] = o;
                else                 ((f16*)C)[row * ldc + col] = (f16)o;
            }
        }
    }
}

// ---------------- weight transpose+convert: Wt[n][k] = f16(W[k][n]) ---------
__global__ __launch_bounds__(256) void wtrans_k(const float* __restrict__ W,
                                                f16* __restrict__ Wt,
                                                int K, int N) {
    __shared__ float t[32][33];
    const int n0 = blockIdx.x * 32, k0 = blockIdx.y * 32;
    const int tx = threadIdx.x & 31, ty = threadIdx.x >> 5;   // 8 rows
#pragma unroll
    for (int i = 0; i < 32; i += 8)
        t[ty + i][tx] = W[(size_t)(k0 + ty + i) * N + n0 + tx];
    __syncthreads();
#pragma unroll
    for (int i = 0; i < 32; i += 8)
        Wt[(size_t)(n0 + ty + i) * K + k0 + tx] = (f16)t[tx][ty + i];
}

// ---------------- x fp32 -> fp16 --------------------------------------------
__global__ __launch_bounds__(256) void f2h_k(const float* __restrict__ x,
                                             f16* __restrict__ xh) {
    size_t i = ((size_t)blockIdx.x * 256 + threadIdx.x) * 4;
    float4 v = *(const float4*)&x[i];
    f16x4 s;
    s.x = (f16)v.x; s.y = (f16)v.y; s.z = (f16)v.z; s.w = (f16)v.w;
    *(f16x4*)&xh[i] = s;
}

// ------- a transform: a_c = sigmoid(|a|)*a/|a| (fp16 in place, x8) ----------
__global__ __launch_bounds__(256) void a_transform_k(f16* __restrict__ a2d) {
    size_t gid = (size_t)blockIdx.x * 256 + threadIdx.x;   // < M*D/8
    int    j8  = (int)(gid & 127) * 8;
    size_t row = gid >> 7;
    f16x8 vr = *(f16x8*)&a2d[row * 2048 + j8];
    f16x8 vi = *(f16x8*)&a2d[row * 2048 + 1024 + j8];
#pragma unroll
    for (int i = 0; i < 8; ++i) {
        float ar = (float)vr[i], ai = (float)vi[i];
        float mag = sqrtf(ar * ar + ai * ai);
        float sg  = fast_sigmoid(mag);
        float re, im;
        if (mag > 1e-30f) { float s = sg * __builtin_amdgcn_rcpf(mag); re = ar * s; im = ai * s; }
        else              { re = sg; im = 0.0f; }
        vr[i] = (f16)re; vi[i] = (f16)im;
    }
    *(f16x8*)&a2d[row * 2048 + j8]        = vr;
    *(f16x8*)&a2d[row * 2048 + 1024 + j8] = vi;
}

// ---------------- chunked complex scan (fp32 state) -------------------------
// P columns: q 0..1023 | k 1024..2047 | v 2048..3071 | g 3072..4095
__global__ __launch_bounds__(256) void scan_pass1_k(const f16* __restrict__ a2d,
                                                    const f16* __restrict__ P,
                                                    float4* __restrict__ chunk) {
    int tid = blockIdx.x * 256 + threadIdx.x;    // < CBD
    int d   = tid & 1023;
    int t1  = tid >> 10;
    int b   = t1 & 3;
    int c   = t1 >> 2;
    int t0  = c * CLEN;
    int rbase = b * Ss;
    float Are = 1.0f, Aim = 0.0f, Hre = 0.0f, Him = 0.0f;
    for (int t = t0; t < t0 + CLEN; ++t) {
        int r = rbase + t;
        float are = (float)a2d[(size_t)r * 2048 + d];
        float aim = (float)a2d[(size_t)r * 2048 + 1024 + d];
        float kvv = (float)P[(size_t)r * PLD + 1024 + d]
                  * (float)P[(size_t)r * PLD + 2048 + d];
        float hre = are * Hre - aim * Him + kvv;
        float him = are * Him + aim * Hre;
        Hre = hre; Him = him;
        float pre = are * Are - aim * Aim;
        float pim = are * Aim + aim * Are;
        Are = pre; Aim = pim;
    }
    chunk[tid] = make_float4(Are, Aim, Hre, Him);
}

__global__ __launch_bounds__(256) void scan_pass2_k(const float4* __restrict__ chunk,
                                                    float2* __restrict__ carry,
                                                    float* __restrict__ stats) {
    int tid = blockIdx.x * blockDim.x + threadIdx.x;  // < B*D = 4096
    if (tid < 512) stats[tid] = 0.0f;                 // ws is poisoned: zero gn stats
    float hre = 0.0f, him = 0.0f;
    for (int c = 0; c < CHUNKS; ++c) {
        int task = c * BD + tid;
        float4 ch = chunk[task];
        carry[task] = make_float2(hre, him);
        float nre = ch.x * hre - ch.y * him + ch.z;
        float nim = ch.x * him + ch.y * hre + ch.w;
        hre = nre; him = nim;
    }
}

// pass3: y written in place over P's q columns (per-elem read-then-write)
__global__ __launch_bounds__(256) void scan_pass3_k(const f16* __restrict__ a2d,
                                                    f16* __restrict__ P,
                                                    const float2* __restrict__ carry,
                                                    float* __restrict__ stats) {
    int tid = blockIdx.x * 256 + threadIdx.x;    // < CBD
    int d   = tid & 1023;
    int t1  = tid >> 10;
    int b   = t1 & 3;
    int c   = t1 >> 2;
    int t0  = c * CLEN;
    int rbase = b * Ss;
    float2 cr = carry[tid];
    float hre = cr.x, him = cr.y;
    float sre = 0.0f, sim = 0.0f, s2 = 0.0f;
    for (int t = t0; t < t0 + CLEN; ++t) {
        int r = rbase + t;
        float are = (float)a2d[(size_t)r * 2048 + d];
        float aim = (float)a2d[(size_t)r * 2048 + 1024 + d];
        float kvv = (float)P[(size_t)r * PLD + 1024 + d]
                  * (float)P[(size_t)r * PLD + 2048 + d];
        float nre = are * hre - aim * him + kvv;
        float nim = are * him + aim * hre;
        hre = nre; him = nim;
        float qv  = (float)P[(size_t)r * PLD + d];
        float yr_ = qv * hre;
        float yi_ = qv * him;
        P[(size_t)r * PLD + d] = (f16)yr_;       // overwrite q with y (safe)
        sre += yr_; sim += yi_; s2 += yr_ * yr_ + yi_ * yi_;
    }
#pragma unroll
    for (int off = 16; off > 0; off >>= 1) {
        sre += __shfl_down(sre, off, 32);
        sim += __shfl_down(sim, off, 32);
        s2  += __shfl_down(s2,  off, 32);
    }
    if ((threadIdx.x & 31) == 0) {
        int idx = (b * 32 + (d >> 5)) * 4;
        atomicAdd(&stats[idx + 0], sre);
        atomicAdd(&stats[idx + 1], sim);
        atomicAdd(&stats[idx + 2], s2);
    }
}

// ------- groupnorm (real) + silu(g)-gate, f16x8, in place on y cols ---------
__global__ __launch_bounds__(256) void gn_gate_k(f16* __restrict__ P,
                                                 const float* __restrict__ stats,
                                                 const float* __restrict__ gn_scale,
                                                 const float* __restrict__ gn_bias) {
    size_t gid = (size_t)blockIdx.x * 256 + threadIdx.x;  // < M*D/8
    int d8  = (int)(gid & 127) * 8;
    int row = (int)(gid >> 7);
    int b   = row >> 12;
    int grp = d8 >> 5;
    const float* st = &stats[(b * 32 + grp) * 4];
    const float invN = 1.0f / 131072.0f;       // S * (D/G)
    float mre = st[0] * invN;
    float mim = st[1] * invN;
    float var = st[2] * invN - mre * mre - mim * mim;
    float rstd = rsqrtf(var + EPSN);
    f16x8 yv = *(f16x8*)&P[(size_t)row * PLD + d8];
    f16x8 gv = *(const f16x8*)&P[(size_t)row * PLD + 3072 + d8];
#pragma unroll
    for (int i = 0; i < 8; ++i) {
        float re = ((float)yv[i] - mre) * rstd * gn_scale[d8 + i] + gn_bias[d8 + i];
        float gx = (float)gv[i];
        yv[i] = (f16)(re * gx * fast_sigmoid(gx));
    }
    *(f16x8*)&P[(size_t)row * PLD + d8] = yv;
}

// ---------------- layernorm over D=1024: out = LN(a + b) --------------------
__device__ __forceinline__ float ldf(const float* p, size_t i) { return p[i]; }
__device__ __forceinline__ float ldf(const f16* p, size_t i)   { return (float)p[i]; }
__device__ __forceinline__ void  stf(float* p, size_t i, float v) { p[i] = v; }
__device__ __forceinline__ void  stf(f16* p, size_t i, float v)   { p[i] = (f16)v; }

__device__ __forceinline__ float block_reduce_sum(float v, float* s4, int tid) {
#pragma unroll
    for (int off = 32; off > 0; off >>= 1) v += __shfl_down(v, off, 64);
    __syncthreads();
    if ((tid & 63) == 0) s4[tid >> 6] = v;
    __syncthreads();
    return s4[0] + s4[1] + s4[2] + s4[3];
}

template <typename TA, typename TB, typename TO>
__global__ __launch_bounds__(256) void ln_k(const TA* __restrict__ a,
                                            const TB* __restrict__ b,
                                            const float* __restrict__ scale,
                                            const float* __restrict__ bias,
                                            TO* __restrict__ out) {
    __shared__ float s4[4];
    int row = blockIdx.x;
    size_t base = (size_t)row * 1024;
    int tid = threadIdx.x;
    float v[4];
    float s = 0.0f;
#pragma unroll
    for (int i = 0; i < 4; ++i) {
        int d = tid + i * 256;
        v[i] = ldf(a, base + d) + ldf(b, base + d);
        s += v[i];
    }
    float mu = block_reduce_sum(s, s4, tid) * (1.0f / 1024.0f);
    float s2 = 0.0f;
#pragma unroll
    for (int i = 0; i < 4; ++i) {
        float dv = v[i] - mu;
        s2 += dv * dv;
    }
    float var = block_reduce_sum(s2, s4, tid) * (1.0f / 1024.0f);
    float rstd = rsqrtf(var + EPSN);
#pragma unroll
    for (int i = 0; i < 4; ++i) {
        int d = tid + i * 256;
        stf(out, base + d, (v[i] - mu) * rstd * scale[d] + bias[d]);
    }
}

// ---------------------------------------------------------------------------
extern "C" void kernel_launch(void* const* d_in, const int* in_sizes, int n_in,
                              void* d_out, int out_size, void* d_ws, size_t ws_size,
                              hipStream_t stream) {
    const float* x        = (const float*)d_in[0];
    const float* Wq       = (const float*)d_in[1];
    const float* Wk       = (const float*)d_in[2];
    const float* Wv       = (const float*)d_in[3];
    const float* Wa       = (const float*)d_in[4];
    const float* Wg       = (const float*)d_in[5];
    const float* Wo       = (const float*)d_in[6];
    const float* gn_scale = (const float*)d_in[7];
    const float* gn_bias  = (const float*)d_in[8];
    const float* ln1_s    = (const float*)d_in[9];
    const float* ln1_b    = (const float*)d_in[10];
    const float* W1       = (const float*)d_in[11];
    const float* b1       = (const float*)d_in[12];
    const float* W2       = (const float*)d_in[13];
    const float* b2       = (const float*)d_in[14];
    const float* ln2_s    = (const float*)d_in[15];
    const float* ln2_b    = (const float*)d_in[16];
    float* out = (float*)d_out;

    char* base = (char*)d_ws;
    f16* W1T = (f16*)(base + 0 * MiB);    // [4096, 1024]
    f16* W2T = (f16*)(base + 8 * MiB);    // [1024, 4096]
    f16* PWT = (f16*)(base + 16 * MiB);   // [4096, 1024] = [Wq|Wk|Wv|Wg]^T
    f16* WoT = (f16*)(base + 24 * MiB);   // [1024, 1024]
    f16* WaT = (f16*)(base + 26 * MiB);   // [2048, 1024]
    float4* chunk = (float4*)(base + 30 * MiB);
    float2* carry = (float2*)(base + 34 * MiB);
    float*  stats = (float*)(base + 36 * MiB);
    f16* xb  = (f16*)(base + 37 * MiB);   // [M,1024] fp16 = 32 MiB
    f16* P   = (f16*)(base + 69 * MiB);   // [M,4096] fp16 = 128 MiB, ends 197
    // aliases (lifetimes verified):
    f16*   ab = (f16*)d_out;              // [M,2048] fp16 = 64 MiB; dead after pass3
    f16*   yo = (f16*)d_out;              // Wo out [M,1024] f16; a dead by then
    f16*   x1 = xb;                       // post-ln1; xb dead after projections
    f16*   h1 = P;                        // [M,F] f16 = 128 MiB; P dead after Wo
    float* h2 = (float*)d_out;            // fp32 [M,D]; yo dead after ln1

    dim3 blk(256);
    dim3 gblk(512);

    // 0. conversions (PWT rows: 0 q | 1024 k | 2048 v | 3072 g)
    f2h_k<<<Mrows, blk, 0, stream>>>(x, xb);
    wtrans_k<<<dim3(128, 32), blk, 0, stream>>>(W1, W1T, Dd, Ff);
    wtrans_k<<<dim3(32, 128), blk, 0, stream>>>(W2, W2T, Ff, Dd);
    wtrans_k<<<dim3(32, 32),  blk, 0, stream>>>(Wq, PWT + 0u * 1048576, Dd, Dd);
    wtrans_k<<<dim3(32, 32),  blk, 0, stream>>>(Wk, PWT + 1u * 1048576, Dd, Dd);
    wtrans_k<<<dim3(32, 32),  blk, 0, stream>>>(Wv, PWT + 2u * 1048576, Dd, Dd);
    wtrans_k<<<dim3(32, 32),  blk, 0, stream>>>(Wg, PWT + 3u * 1048576, Dd, Dd);
    wtrans_k<<<dim3(32, 32),  blk, 0, stream>>>(Wo, WoT, Dd, Dd);
    wtrans_k<<<dim3(64, 32),  blk, 0, stream>>>(Wa, WaT, Dd, 2 * Dd);

    // 1. projections: one N=4096 GEMM (q|k|v|g) + one N=2048 (a)
    mgemm_k<0, f16><<<dim3(16, 64), gblk, 0, stream>>>(xb, Dd, PWT, P, PLD, Mrows, 4096, Dd, nullptr);
    mgemm_k<0, f16><<<dim3(8, 64),  gblk, 0, stream>>>(xb, Dd, WaT, ab, 2048, Mrows, 2048, Dd, nullptr);

    // 2. a transform (fp16, in place in d_out)
    a_transform_k<<<MD / (256 * 8), blk, 0, stream>>>(ab);

    // 3. chunked scan (k*v inline; y in-place over q cols of P)
    scan_pass1_k<<<CBD / 256, blk, 0, stream>>>(ab, P, chunk);
    scan_pass2_k<<<BD / 256, blk, 0, stream>>>(chunk, carry, stats);
    scan_pass3_k<<<CBD / 256, blk, 0, stream>>>(ab, P, carry, stats);

    // 4. groupnorm + silu(g) gate (in place on y cols of P)
    gn_gate_k<<<MD / (256 * 8), blk, 0, stream>>>(P, stats, gn_scale, gn_bias);

    // 5. output projection (A = y cols of P, lda=PLD) + ln1
    mgemm_k<0, f16><<<dim3(4, 64), gblk, 0, stream>>>(P, PLD, WoT, yo, Dd, Mrows, Dd, Dd, nullptr);
    ln_k<float, f16, f16><<<Mrows, blk, 0, stream>>>(x, yo, ln1_s, ln1_b, x1);

    // 6. MLP (h1 overlays P; h2 -> d_out fp32)
    mgemm_k<1, f16  ><<<dim3(16, 64), gblk, 0, stream>>>(x1, Dd, W1T, h1, Ff, Mrows, Ff, Dd, b1);
    mgemm_k<2, float><<<dim3(4, 64),  gblk, 0, stream>>>(h1, Ff, W2T, h2, Dd, Mrows, Dd, Ff, b2);

    // 7. final layernorm -> out (in place over h2: per-thread read-then-write)
    ln_k<f16, float, float><<<Mrows, blk, 0, stream>>>(x1, h2, ln2_s, ln2_b, out);
}